// Round 2
// baseline (284.646 us; speedup 1.0000x reference)
//
#include <hip/hip_runtime.h>
#include <hip/hip_bf16.h>

// DotProductNonLocalBlock: B=8, C=512, N=3136 (pad 3200), E=256.
// No softmax => fully associative. Factored with DATA-INDEPENDENT
// P = wo·wv, Qt = wq^T·wk, u = wo·bv, r = bk^T·wq, w = Wk^T·bq, κ = bk·bq:
//   G  = X·X^T   [bf16 MFMA, split-K=2 col-interleaved partials, SYMMETRIC:
//                 only upper-triangular tile pairs computed, mirrored on store]
//   T  = Pd·Gp2 (K=1024 folds the reduce)
//   A2 = [T·Q + u·(Qt s)^T + (P s)·r^T]/N + u·r^T
//   a2 = [T·w + u·(s·w) + (P s)·κ]/N + u·κ + bo
//   Out = A2·X + a2 + X
// All MFMA grids put batch in blockIdx.x (XCD affinity: per-batch slices fit 4MB L2
// — round-6 verified: FETCH 144->53MB on the final GEMM).
// Round 7: mfma_g/mfma_sm double-buffered 2-phase K-loops (~neutral, kept).
// mfma64 dbuf REGRESSED (occ 21->16%, LDS 48KB occupancy cliff; FETCH +13MB).
// Round 8: mfma64 rewritten as zero-LDS zero-barrier streaming MFMA: B rows are
// consumed by exactly one wave (LDS staging bought nothing), A is L2-resident;
// direct-global fragment loads are 16x fully-consumed 64B lines per instr.

typedef __attribute__((ext_vector_type(8))) __bf16 bf16x8;
typedef __attribute__((ext_vector_type(4))) float floatx4;

struct __align__(8) bh4 { __hip_bfloat16 x, y, z, w; };
struct __align__(16) bh8 { __hip_bfloat16 h[8]; };

__device__ __forceinline__ void load_lds16(const void* g, void* l) {
    __builtin_amdgcn_global_load_lds((const __attribute__((address_space(1))) void*)g,
                                     (__attribute__((address_space(3))) void*)l, 16, 0, 0);
}

// ---- fused data-independent precompute ----
// z=0: Pd=[P|P] (bf16 512x1024, P=wo·wv).  z=1: Qt (bf16 512x512, wq^T·wk).
// z=2: blocks 0,1 -> u/r/w/kap vectors; block 2 -> zero s accumulator.
__global__ __launch_bounds__(256)
void prep_all(const float* __restrict__ wo, const float* __restrict__ wv,
              const float* __restrict__ wq, const float* __restrict__ wk,
              const float* __restrict__ bq, const float* __restrict__ bk,
              const float* __restrict__ bv,
              __hip_bfloat16* __restrict__ Pdb, __hip_bfloat16* __restrict__ Qtb,
              float* __restrict__ u, float* __restrict__ r, float* __restrict__ w,
              float* __restrict__ kap, float* __restrict__ sv)
{
    const int tid = threadIdx.x;
    if (blockIdx.z == 2) {
        int blk = blockIdx.y * 8 + blockIdx.x;
        if (blk < 2) {
            int c = blk * 256 + tid;
            float su = 0.f, sr = 0.f, sw = 0.f;
            for (int e = 0; e < 256; ++e) {
                su = fmaf(wo[(long long)c * 256 + e], bv[e], su);
                sr = fmaf(bk[e], wq[(long long)e * 512 + c], sr);
                sw = fmaf(wk[(long long)e * 512 + c], bq[e], sw);
            }
            u[c] = su; r[c] = sr; w[c] = sw;
            if (c == 0) {
                float k2 = 0.f;
                for (int e = 0; e < 256; ++e) k2 = fmaf(bk[e], bq[e], k2);
                *kap = k2;
            }
        } else if (blk == 2) {
            float4* p = (float4*)sv;
            for (int i = tid; i < 1024; i += 256) p[i] = make_float4(0.f, 0.f, 0.f, 0.f);
        }
        return;
    }
    __shared__ __align__(16) float As[16][68];
    __shared__ __align__(16) float Bs[16][68];
    const int tx = tid & 15, ty = tid >> 4;
    const int m0 = blockIdx.y * 64, n0 = blockIdx.x * 64;
    const bool doQ = (blockIdx.z == 1);
    const int lk = tid >> 4, lc = (tid & 15) * 4;
    const int lr = tid >> 2, lk4 = (tid & 3) * 4;
    float acc[4][4] = {};
    for (int k0 = 0; k0 < 256; k0 += 16) {
        float4 av, bv4;
        if (doQ) {
            av = *(const float4*)&wq[(long long)(k0 + lk) * 512 + m0 + lc];
            bv4 = *(const float4*)&wk[(long long)(k0 + lk) * 512 + n0 + lc];
        } else {
            av = *(const float4*)&wo[(long long)(m0 + lr) * 256 + k0 + lk4];
            bv4 = *(const float4*)&wv[(long long)(k0 + lk) * 512 + n0 + lc];
        }
        __syncthreads();
        if (doQ) {
            *(float4*)&As[lk][lc] = av;
        } else {
            As[lk4 + 0][lr] = av.x; As[lk4 + 1][lr] = av.y;
            As[lk4 + 2][lr] = av.z; As[lk4 + 3][lr] = av.w;
        }
        *(float4*)&Bs[lk][lc] = bv4;
        __syncthreads();
#pragma unroll
        for (int kk = 0; kk < 16; ++kk) {
            float a[4], b[4];
#pragma unroll
            for (int i = 0; i < 4; ++i) { a[i] = As[kk][ty * 4 + i]; b[i] = Bs[kk][tx * 4 + i]; }
#pragma unroll
            for (int i = 0; i < 4; ++i)
#pragma unroll
                for (int j = 0; j < 4; ++j) acc[i][j] = fmaf(a[i], b[j], acc[i][j]);
        }
    }
    const int mo = m0 + ty * 4, no = n0 + tx * 4;
    if (doQ) {
#pragma unroll
        for (int i = 0; i < 4; ++i)
#pragma unroll
            for (int j = 0; j < 4; ++j)
                Qtb[(long long)(mo + i) * 512 + no + j] = __float2bfloat16(acc[i][j]);
    } else {
#pragma unroll
        for (int i = 0; i < 4; ++i)
#pragma unroll
            for (int j = 0; j < 4; ++j) {
                __hip_bfloat16 v = __float2bfloat16(acc[i][j]);
                Pdb[(long long)(mo + i) * 1024 + no + j] = v;
                Pdb[(long long)(mo + i) * 1024 + no + j + 512] = v;
            }
    }
}

// x [b][512][3136] fp32 -> xT [b][3200][512] bf16 (pad rows zero)
//                        + xnp [b][512][3200] bf16 (pad cols zero)
//                        + s[b][c] += rowsums (atomic)
// All global stores are 16B (bh8); LDS round-trip for the transpose.
__global__ __launch_bounds__(256)
void transpose_conv(const float* __restrict__ x, __hip_bfloat16* __restrict__ xT,
                    __hip_bfloat16* __restrict__ xnp, float* __restrict__ s)
{
    __shared__ float t[64][65];
    const int b = blockIdx.z;
    const int n0 = blockIdx.x * 64, c0 = blockIdx.y * 64;
    const int tid = threadIdx.x;
    const int nch = tid & 7;      // 8-wide chunk index
    const int cr  = tid >> 3;     // 0..31 row-within-pass
    __hip_bfloat16* xTo = xT + (long long)b * 3200 * 512;
    __hip_bfloat16* xno = xnp + (long long)b * 512 * 3200;

    if (n0 >= 3136) {             // pad tile
        bh8 z8;
#pragma unroll
        for (int k = 0; k < 8; ++k) z8.h[k] = __float2bfloat16(0.f);
#pragma unroll
        for (int pass = 0; pass < 2; ++pass) {
            int rr = cr + 32 * pass;
            *(bh8*)&xno[(long long)(c0 + rr) * 3200 + n0 + nch * 8] = z8;
            *(bh8*)&xTo[(long long)(n0 + rr) * 512 + c0 + nch * 8] = z8;
        }
        return;
    }
    const float* xb = x + (long long)b * 512 * 3136;
#pragma unroll
    for (int pass = 0; pass < 2; ++pass) {
        const int cl = cr + 32 * pass;
        const int c = c0 + cl;
        const float* xr = xb + (long long)c * 3136 + n0 + nch * 8;
        float4 v0 = *(const float4*)xr;
        float4 v1 = *(const float4*)(xr + 4);
        bh8 o;
        o.h[0] = __float2bfloat16(v0.x); o.h[1] = __float2bfloat16(v0.y);
        o.h[2] = __float2bfloat16(v0.z); o.h[3] = __float2bfloat16(v0.w);
        o.h[4] = __float2bfloat16(v1.x); o.h[5] = __float2bfloat16(v1.y);
        o.h[6] = __float2bfloat16(v1.z); o.h[7] = __float2bfloat16(v1.w);
        *(bh8*)&xno[(long long)c * 3200 + n0 + nch * 8] = o;
        const int nl = nch * 8;
        t[nl + 0][cl] = v0.x; t[nl + 1][cl] = v0.y;
        t[nl + 2][cl] = v0.z; t[nl + 3][cl] = v0.w;
        t[nl + 4][cl] = v1.x; t[nl + 5][cl] = v1.y;
        t[nl + 6][cl] = v1.z; t[nl + 7][cl] = v1.w;
        float rs = v0.x + v0.y + v0.z + v0.w + v1.x + v1.y + v1.z + v1.w;
        rs += __shfl_xor(rs, 1, 8);
        rs += __shfl_xor(rs, 2, 8);
        rs += __shfl_xor(rs, 4, 8);
        if (nch == 0) atomicAdd(&s[b * 512 + c], rs);
    }
    __syncthreads();
#pragma unroll
    for (int pass = 0; pass < 2; ++pass) {
        const int nl = cr + 32 * pass;
        const int cc = nch * 8;
        bh8 o;
#pragma unroll
        for (int k = 0; k < 8; ++k) o.h[k] = __float2bfloat16(t[nl][cc + k]);
        *(bh8*)&xTo[(long long)(n0 + nl) * 512 + c0 + cc] = o;
    }
}

// Wave-per-output: ps = P·s, sq = Qt·s, a2 = [T·w + u(s·w) + ps·κ]/N + uκ + bo.
__global__ __launch_bounds__(256)
void vec2_kernel(const __hip_bfloat16* __restrict__ T, const __hip_bfloat16* __restrict__ Pdb,
                 const __hip_bfloat16* __restrict__ Qtb, const float* __restrict__ s,
                 const float* __restrict__ u, const float* __restrict__ w,
                 const float* __restrict__ kap, const float* __restrict__ bo,
                 float* __restrict__ ps, float* __restrict__ sq, float* __restrict__ a2)
{
    const int idx = blockIdx.x * 4 + (threadIdx.x >> 6);   // b*512+c
    const int lane = threadIdx.x & 63;
    const int b = idx >> 9, c = idx & 511;
    const int j0 = lane * 8;
    const float* sb = s + b * 512;
    float4 s0 = *(const float4*)&sb[j0], s1 = *(const float4*)&sb[j0 + 4];
    float4 w0 = *(const float4*)&w[j0],  w1 = *(const float4*)&w[j0 + 4];
    bf16x8 pv = *(const bf16x8*)&Pdb[(long long)c * 1024 + j0];
    bf16x8 qv = *(const bf16x8*)&Qtb[(long long)c * 512 + j0];
    bf16x8 tv = *(const bf16x8*)&T[(long long)b * 262144 + (long long)c * 512 + j0];
    float sj[8] = {s0.x, s0.y, s0.z, s0.w, s1.x, s1.y, s1.z, s1.w};
    float wj[8] = {w0.x, w0.y, w0.z, w0.w, w1.x, w1.y, w1.z, w1.w};
    float aps = 0.f, asq = 0.f, atw = 0.f, asw = 0.f;
#pragma unroll
    for (int t = 0; t < 8; ++t) {
        aps = fmaf((float)pv[t], sj[t], aps);
        asq = fmaf((float)qv[t], sj[t], asq);
        atw = fmaf((float)tv[t], wj[t], atw);
        asw = fmaf(sj[t], wj[t], asw);
    }
#pragma unroll
    for (int m = 1; m < 64; m <<= 1) {
        aps += __shfl_xor(aps, m);
        asq += __shfl_xor(asq, m);
        atw += __shfl_xor(atw, m);
        asw += __shfl_xor(asw, m);
    }
    if (lane == 0) {
        ps[idx] = aps; sq[idx] = asq;
        float kp = *kap;
        a2[idx] = (atw + u[c] * asw + aps * kp) * (1.f / 3136.f) + u[c] * kp + bo[c];
    }
}

#define SWZ64(row) ((row) & 7)

// G GEMM with symmetric mirroring. 64x64 tile, BK=64, operands = xnp (both).
// Grid: x = batch + 8*ks (XCD affinity), y = triangular pair index (36).
// Double-buffered 2-phase K-loop: stage(kt+1) -> compute(kt) -> syncthreads.
__global__ __launch_bounds__(256)
void mfma_g(const __hip_bfloat16* __restrict__ A, long long sA, int lda,
            __hip_bfloat16* __restrict__ C, long long sC, int ldc,
            int kLen)
{
    constexpr int BKT = 64;
    constexpr int CPR = BKT / 8;
    constexpr int NC = 64 * CPR / 256;
    constexpr int LSZ = 64 * BKT;
    __shared__ __hip_bfloat16 As[2 * LSZ];
    __shared__ __hip_bfloat16 Bs[2 * LSZ];
    const int tid = threadIdx.x;
    const int lane = tid & 63;
    const int w = tid >> 6;
    const int wm = (w >> 1) << 5;
    const int wn = (w & 1) << 5;
    const int ln = lane & 15;
    const int hi = lane >> 4;
    const int bx = blockIdx.x;
    const int batch = bx & 7, ks = bx >> 3;
    int p = blockIdx.y, mt = 0;
    while (p >= 8 - mt) { p -= 8 - mt; ++mt; }
    const int nt = mt + p;
    const int m0 = mt << 6, n0 = nt << 6;
    const long long k0 = (long long)ks * kLen;

    const __hip_bfloat16* gA[NC];
    const __hip_bfloat16* gB[NC];
#pragma unroll
    for (int q0 = 0; q0 < NC; ++q0) {
        int q = tid + 256 * q0;
        int row = q / CPR;
        int c = (q % CPR) ^ SWZ64(row);
        gA[q0] = A + batch * sA + (long long)(m0 + row) * lda + k0 + c * 8;
        gB[q0] = A + batch * sA + (long long)(n0 + row) * lda + k0 + c * 8;
    }
    floatx4 acc[2][2] = {};
    const int nK = kLen / BKT;

    // prologue: stage tile 0 into buffer 0
#pragma unroll
    for (int q0 = 0; q0 < NC; ++q0) {
        load_lds16(gA[q0], As + (tid + 256 * q0) * 8);
        load_lds16(gB[q0], Bs + (tid + 256 * q0) * 8);
        gA[q0] += BKT; gB[q0] += BKT;
    }
    __syncthreads();

    int cur = 0;
    for (int kt = 0; kt < nK; ++kt) {
        if (kt + 1 < nK) {
            const int off = (cur ^ 1) * LSZ;
#pragma unroll
            for (int q0 = 0; q0 < NC; ++q0) {
                load_lds16(gA[q0], As + off + (tid + 256 * q0) * 8);
                load_lds16(gB[q0], Bs + off + (tid + 256 * q0) * 8);
                gA[q0] += BKT; gB[q0] += BKT;
            }
        }
        const __hip_bfloat16* Ac = As + cur * LSZ;
        const __hip_bfloat16* Bc = Bs + cur * LSZ;
#pragma unroll
        for (int kk = 0; kk < BKT / 32; ++kk) {
            const int cidx = kk * 4 + hi;
            bf16x8 af[2], bfr[2];
#pragma unroll
            for (int i = 0; i < 2; ++i) {
                int row = wm + i * 16 + ln;
                af[i] = *(const bf16x8*)(Ac + row * BKT + ((cidx ^ SWZ64(row)) << 3));
            }
#pragma unroll
            for (int j = 0; j < 2; ++j) {
                int row = wn + j * 16 + ln;
                bfr[j] = *(const bf16x8*)(Bc + row * BKT + ((cidx ^ SWZ64(row)) << 3));
            }
#pragma unroll
            for (int i = 0; i < 2; ++i)
#pragma unroll
                for (int j = 0; j < 2; ++j)
                    acc[i][j] = __builtin_amdgcn_mfma_f32_16x16x32_bf16(af[i], bfr[j], acc[i][j], 0, 0, 0);
        }
        if (kt + 1 < nK) {
            __syncthreads();   // drains vmcnt (next stage landed) + lgkmcnt (buf consumed)
            cur ^= 1;
        }
    }

    // C/D layout: col = lane&15, row = (lane>>4)*4 + r  [m89-verified]
    __hip_bfloat16* Cb = C + batch * sC + ks * 512;
#pragma unroll
    for (int i = 0; i < 2; ++i) {
        int mb = m0 + wm + i * 16 + hi * 4;
#pragma unroll
        for (int j = 0; j < 2; ++j) {
            int nl = n0 + wn + j * 16 + ln;
            bh4 mv;
            mv.x = __float2bfloat16(acc[i][j][0]);
            mv.y = __float2bfloat16(acc[i][j][1]);
            mv.z = __float2bfloat16(acc[i][j][2]);
            mv.w = __float2bfloat16(acc[i][j][3]);
            Cb[(long long)(mb + 0) * ldc + nl] = mv.x;
            Cb[(long long)(mb + 1) * ldc + nl] = mv.y;
            Cb[(long long)(mb + 2) * ldc + nl] = mv.z;
            Cb[(long long)(mb + 3) * ldc + nl] = mv.w;
            if (mt != nt)
                *(bh4*)&Cb[(long long)nl * ldc + mb] = mv;   // mirrored tile
        }
    }
}

// Small MFMA GEMM, 64x64 tile, BK=64, operands K-contiguous.
// Grid: x = batch, y = n-tile, z = m-tile.
// MODE 5: plain bf16 store.
// MODE 6: bf16 store of (acc + u[m]·sq[b][n] + ps[b][m]·r[n])/N + u[m]·r[n].
// Double-buffered 2-phase K-loop.
template<int MODE>
__global__ __launch_bounds__(256)
void mfma_sm(const __hip_bfloat16* __restrict__ A, long long sA, int lda,
             const __hip_bfloat16* __restrict__ B, long long sB, int ldb,
             __hip_bfloat16* __restrict__ C, long long sC, int ldc,
             const float* __restrict__ pu, const float* __restrict__ pr,
             const float* __restrict__ pps, const float* __restrict__ psq,
             int kLen)
{
    constexpr int BKT = 64;
    constexpr int CPR = BKT / 8;
    constexpr int NC = 64 * CPR / 256;
    constexpr int LSZ = 64 * BKT;
    __shared__ __hip_bfloat16 As[2 * LSZ];
    __shared__ __hip_bfloat16 Bs[2 * LSZ];
    const int tid = threadIdx.x;
    const int lane = tid & 63;
    const int w = tid >> 6;
    const int wm = (w >> 1) << 5;
    const int wn = (w & 1) << 5;
    const int ln = lane & 15;
    const int hi = lane >> 4;
    const int batch = blockIdx.x;
    const int m0 = blockIdx.z << 6;
    const int n0 = blockIdx.y << 6;

    const __hip_bfloat16* gA[NC];
    const __hip_bfloat16* gB[NC];
#pragma unroll
    for (int q0 = 0; q0 < NC; ++q0) {
        int q = tid + 256 * q0;
        int row = q / CPR;
        int c = (q % CPR) ^ SWZ64(row);
        gA[q0] = A + batch * sA + (long long)(m0 + row) * lda + c * 8;
        gB[q0] = B + batch * sB + (long long)(n0 + row) * ldb + c * 8;
    }
    floatx4 acc[2][2] = {};
    const int nK = kLen / BKT;

#pragma unroll
    for (int q0 = 0; q0 < NC; ++q0) {
        load_lds16(gA[q0], As + (tid + 256 * q0) * 8);
        load_lds16(gB[q0], Bs + (tid + 256 * q0) * 8);
        gA[q0] += BKT; gB[q0] += BKT;
    }
    __syncthreads();

    int cur = 0;
    for (int kt = 0; kt < nK; ++kt) {
        if (kt + 1 < nK) {
            const int off = (cur ^ 1) * LSZ;
#pragma unroll
            for (int q0 = 0; q0 < NC; ++q0) {
                load_lds16(gA[q0], As + off + (tid + 256 * q0) * 8);
                load_lds16(gB[q0], Bs + off + (tid + 256 * q0) * 8);
                gA[q0] += BKT; gB[q0] += BKT;
            }
        }
        const __hip_bfloat16* Ac = As + cur * LSZ;
        const __hip_bfloat16* Bc = Bs + cur * LSZ;
#pragma unroll
        for (int kk = 0; kk < BKT / 32; ++kk) {
            const int cidx = kk * 4 + hi;
            bf16x8 af[2], bfr[2];
#pragma unroll
            for (int i = 0; i < 2; ++i) {
                int row = wm + i * 16 + ln;
                af[i] = *(const bf16x8*)(Ac + row * BKT + ((cidx ^ SWZ64(row)) << 3));
            }
#pragma unroll
            for (int j = 0; j < 2; ++j) {
                int row = wn + j * 16 + ln;
                bfr[j] = *(const bf16x8*)(Bc + row * BKT + ((cidx ^ SWZ64(row)) << 3));
            }
#pragma unroll
            for (int i = 0; i < 2; ++i)
#pragma unroll
                for (int j = 0; j < 2; ++j)
                    acc[i][j] = __builtin_amdgcn_mfma_f32_16x16x32_bf16(af[i], bfr[j], acc[i][j], 0, 0, 0);
        }
        if (kt + 1 < nK) {
            __syncthreads();
            cur ^= 1;
        }
    }

    __hip_bfloat16* Cb = C + batch * sC;
#pragma unroll
    for (int i = 0; i < 2; ++i) {
        int mb = m0 + wm + i * 16 + hi * 4;
#pragma unroll
        for (int r = 0; r < 4; ++r) {
#pragma unroll
            for (int j = 0; j < 2; ++j) {
                int nl = n0 + wn + j * 16 + ln;
                float v = acc[i][j][r];
                if (MODE == 6) {
                    float uu = pu[mb + r], rr = pr[nl];
                    v = (v + uu * psq[batch * 512 + nl] + pps[batch * 512 + mb + r] * rr)
                        * (1.f / 3136.f) + uu * rr;
                }
                Cb[(long long)(mb + r) * ldc + nl] = __float2bfloat16(v);
            }
        }
    }
}

// Final MFMA GEMM: 64(M)x128(N) tile, 4 waves (64x32 each), K=512.
// ZERO LDS, ZERO BARRIERS: B rows are consumed by exactly one wave (staging
// through LDS bought no sharing, only barrier drains); A (64x512 bf16 = 64KB)
// is read redundantly per wave but is L2-resident (per-batch A2+xT panel
// < 4MB XCD L2 with batch->XCD affinity). Fragment loads: lane(ln,hi) reads
// row(ln)*1KB + hi*16B -> each wave-load touches 16 fully-consumed 64B lines.
// K-offsets are compile-time -> global_load_dwordx4 with folded offset:imm;
// the compiler software-pipelines freely (no syncthreads/vmcnt(0) anywhere).
// Residual x prefetched in the prologue; no drain can kill it now.
__global__ __launch_bounds__(256)
void mfma64(const __hip_bfloat16* __restrict__ A, long long sA, int lda,
            const __hip_bfloat16* __restrict__ B, long long sB, int ldb,
            float* __restrict__ C, long long sC, int ldc,
            const float* __restrict__ bias, int sBias,
            const float* __restrict__ xres, long long sX,
            int kLen, int Nreal)
{
    const int tid = threadIdx.x;
    const int lane = tid & 63;
    const int w = tid >> 6;
    const int ln = lane & 15;
    const int hi = lane >> 4;
    const int batch = blockIdx.x;
    const int m0 = blockIdx.z << 6;
    const int n0 = blockIdx.y << 7;

    // per-lane fragment base pointers (k advances via folded imm offsets)
    const __hip_bfloat16* pa[4];
#pragma unroll
    for (int i = 0; i < 4; ++i)
        pa[i] = A + batch * sA + (long long)(m0 + i * 16 + ln) * lda + hi * 8;
    const __hip_bfloat16* pb[2];
#pragma unroll
    for (int j = 0; j < 2; ++j)
        pb[j] = B + batch * sB + (long long)(n0 + w * 32 + j * 16 + ln) * ldb + hi * 8;

    // residual prefetch — stays in flight under the whole K-loop
    const float* xb = xres + batch * sX;
    float xr[4][4][2];
#pragma unroll
    for (int i = 0; i < 4; ++i)
#pragma unroll
        for (int r = 0; r < 4; ++r)
#pragma unroll
            for (int j = 0; j < 2; ++j) {
                int mb = m0 + i * 16 + hi * 4 + r;
                int nl = n0 + w * 32 + j * 16 + ln;
                int nlc = nl < Nreal ? nl : Nreal - 1;
                xr[i][r][j] = xb[(long long)mb * ldc + nlc];
            }

    floatx4 acc[4][2] = {};
    const int nK = kLen / 32;
#pragma unroll 4
    for (int kc = 0; kc < nK; ++kc) {
        bf16x8 af[4], bfr[2];
#pragma unroll
        for (int i = 0; i < 4; ++i)
            af[i] = *(const bf16x8*)(pa[i] + kc * 32);
#pragma unroll
        for (int j = 0; j < 2; ++j)
            bfr[j] = *(const bf16x8*)(pb[j] + kc * 32);
#pragma unroll
        for (int i = 0; i < 4; ++i)
#pragma unroll
            for (int j = 0; j < 2; ++j)
                acc[i][j] = __builtin_amdgcn_mfma_f32_16x16x32_bf16(af[i], bfr[j], acc[i][j], 0, 0, 0);
    }

    float* Cb = C + batch * sC;
#pragma unroll
    for (int i = 0; i < 4; ++i) {
        int mb = m0 + i * 16 + hi * 4;
#pragma unroll
        for (int r = 0; r < 4; ++r) {
            float bb = bias[batch * sBias + mb + r];
#pragma unroll
            for (int j = 0; j < 2; ++j) {
                int nl = n0 + w * 32 + j * 16 + ln;
                if (nl < Nreal) {
                    Cb[(long long)(mb + r) * ldc + nl] = acc[i][j][r] + bb + xr[i][r][j];
                }
            }
        }
    }
}

extern "C" void kernel_launch(void* const* d_in, const int* in_sizes, int n_in,
                              void* d_out, int out_size, void* d_ws, size_t ws_size,
                              hipStream_t stream)
{
    const float* x  = (const float*)d_in[0];
    const float* wq = (const float*)d_in[1];
    const float* bq = (const float*)d_in[2];
    const float* wk = (const float*)d_in[3];
    const float* bk = (const float*)d_in[4];
    const float* wv = (const float*)d_in[5];
    const float* bv = (const float*)d_in[6];
    const float* wo = (const float*)d_in[7];
    const float* bo = (const float*)d_in[8];
    float* out = (float*)d_out;

    const int N = 3136;
    const long long xs = 512LL * N;               // 1,605,632
    const long long xs2 = 512LL * 3200;           // xnp per-batch stride

    // d_out scratch (51.4 MB), all dead before the final GEMM writes out:
    char* ob = (char*)d_out;
    __hip_bfloat16* xnp = (__hip_bfloat16*)ob;                 // @0: 26,214,400 (dead after G)
    __hip_bfloat16* Gp2 = (__hip_bfloat16*)(ob + 26214400);    // 8x512x1024 bf16 = 8,388,608
    __hip_bfloat16* Tb  = (__hip_bfloat16*)(ob + 34603008);    // 8x512x512 bf16 = 4,194,304

    // ws (~32.05 MB). Final GEMM reads only ws + x.
    char* wsb = (char*)d_ws;
    __hip_bfloat16* xT  = (__hip_bfloat16*)wsb;                // 26,214,400
    __hip_bfloat16* A2b = (__hip_bfloat16*)(wsb + 26214400);   //  4,194,304
    __hip_bfloat16* Pdb = (__hip_bfloat16*)(wsb + 30408704);   //  1,048,576
    __hip_bfloat16* Qtb = (__hip_bfloat16*)(wsb + 31457280);   //    524,288
    float* sv  = (float*)(wsb + 31981568);                     //     16,384
    float* u_  = (float*)(wsb + 31997952);                     //      2,048
    float* r_  = (float*)(wsb + 32000000);                     //      2,048
    float* w_  = (float*)(wsb + 32002048);                     //      2,048
    float* kap = (float*)(wsb + 32004096);                     //         16
    float* ps  = (float*)(wsb + 32004112);                     //     16,384
    float* sq  = (float*)(wsb + 32020496);                     //     16,384
    float* a2v = (float*)(wsb + 32036880);                     //     16,384

    // 1) fused data-independent precompute (P/Qt/u/r/w/kap + zero s)
    prep_all<<<dim3(8, 8, 3), 256, 0, stream>>>(wo, wv, wq, wk, bq, bk, bv,
                                                Pdb, Qtb, u_, r_, w_, kap, sv);

    // 2) xT + xnp + s (16B stores)
    transpose_conv<<<dim3(50, 8, 8), 256, 0, stream>>>(x, xT, xnp, sv);

    // 3) Gp2 = partials of X·X^T  (split-K=2, K=1600, BK=64), symmetric:
    //    36 upper-tri tile pairs x 16 (batch,ks) = 576 blocks, mirror on store
    mfma_g<<<dim3(16, 36), 256, 0, stream>>>(
        xnp, xs2, 3200, Gp2, 524288, 1024, 1600);

    // 4) T = Pd·Gp2  (K=1024 folds the split-K reduce)
    mfma_sm<5><<<dim3(8, 8, 8), 256, 0, stream>>>(
        Pdb, 0, 1024, Gp2, 524288, 1024, Tb, 262144, 512,
        nullptr, nullptr, nullptr, nullptr, 1024);

    // 5) ps = P·s, sq = Qt·s, a2 = [T·w + u(s·w) + ps·κ]/N + uκ + bo
    vec2_kernel<<<1024, 256, 0, stream>>>(Tb, Pdb, Qtb, sv, u_, w_, kap, bo, ps, sq, a2v);

    // 6) A2 = [T·Q + u·sq^T + ps·r^T]/N + u·r^T  -> bf16
    mfma_sm<6><<<dim3(8, 8, 8), 256, 0, stream>>>(
        Tb, 262144, 512, Qtb, 0, 512, A2b, 262144, 512,
        u_, r_, ps, sq, 512);

    // 7) out = A2·X + a2 + x   (M=512, N=3136, K=512)
    mfma64<<<dim3(8, 25, 8), 256, 0, stream>>>(
        A2b, 262144, 512, xT, 3200LL * 512, 512,
        out, xs, N, a2v, 512, x, xs, 512, N);
}

// Round 3
// 239.945 us; speedup vs baseline: 1.1863x; 1.1863x over previous
//
#include <hip/hip_runtime.h>
#include <hip/hip_bf16.h>

// DotProductNonLocalBlock: B=8, C=512, N=3136 (pad 3200), E=256.
// No softmax => fully associative. Factored with DATA-INDEPENDENT
// P = wo·wv, Qt = wq^T·wk, u = wo·bv, r = bk^T·wq, w = Wk^T·bq, κ = bk·bq:
//   G  = X·X^T   [bf16 MFMA, split-K=2 col-interleaved partials, SYMMETRIC]
//   T  = Pd·Gp2 (K=1024 folds the reduce)
//   A2 = [T·Q + u·(Qt s)^T + (P s)·r^T]/N + u·r^T
//   a2 = [T·w + u·(s·w) + (P s)·κ]/N + u·κ + bo
//   Out = A2·X + a2 + X
// Batch in blockIdx.x on all MFMA grids (XCD affinity; per-batch panels fit 4MB L2).
// Round 7: mfma_g/mfma_sm dbuf 2-phase (net ~-1us, kept).
// Round 8: zero-LDS mfma64 FAILED HARD (107us, MfmaUtil 4.7%, VGPR 68 — compiler
//   won't register-pipeline flat loads; LDS staging is load-bearing).
// Round 9: final GEMM back to the proven m97-style 2-barrier single-buffer loop,
//   tile 64x128 -> 128x128 (guide tile-space: 64²=343 vs 128²=912 TF on this exact
//   structure): 2x MFMA per staged byte, half the total staging traffic.
//   Residual x read in the epilogue (prologue prefetch would cost 64 VGPRs).

typedef __attribute__((ext_vector_type(8))) __bf16 bf16x8;
typedef __attribute__((ext_vector_type(4))) float floatx4;

struct __align__(8) bh4 { __hip_bfloat16 x, y, z, w; };
struct __align__(16) bh8 { __hip_bfloat16 h[8]; };

__device__ __forceinline__ void load_lds16(const void* g, void* l) {
    __builtin_amdgcn_global_load_lds((const __attribute__((address_space(1))) void*)g,
                                     (__attribute__((address_space(3))) void*)l, 16, 0, 0);
}

// ---- fused data-independent precompute ----
// z=0: Pd=[P|P] (bf16 512x1024, P=wo·wv).  z=1: Qt (bf16 512x512, wq^T·wk).
// z=2: blocks 0,1 -> u/r/w/kap vectors; block 2 -> zero s accumulator.
__global__ __launch_bounds__(256)
void prep_all(const float* __restrict__ wo, const float* __restrict__ wv,
              const float* __restrict__ wq, const float* __restrict__ wk,
              const float* __restrict__ bq, const float* __restrict__ bk,
              const float* __restrict__ bv,
              __hip_bfloat16* __restrict__ Pdb, __hip_bfloat16* __restrict__ Qtb,
              float* __restrict__ u, float* __restrict__ r, float* __restrict__ w,
              float* __restrict__ kap, float* __restrict__ sv)
{
    const int tid = threadIdx.x;
    if (blockIdx.z == 2) {
        int blk = blockIdx.y * 8 + blockIdx.x;
        if (blk < 2) {
            int c = blk * 256 + tid;
            float su = 0.f, sr = 0.f, sw = 0.f;
            for (int e = 0; e < 256; ++e) {
                su = fmaf(wo[(long long)c * 256 + e], bv[e], su);
                sr = fmaf(bk[e], wq[(long long)e * 512 + c], sr);
                sw = fmaf(wk[(long long)e * 512 + c], bq[e], sw);
            }
            u[c] = su; r[c] = sr; w[c] = sw;
            if (c == 0) {
                float k2 = 0.f;
                for (int e = 0; e < 256; ++e) k2 = fmaf(bk[e], bq[e], k2);
                *kap = k2;
            }
        } else if (blk == 2) {
            float4* p = (float4*)sv;
            for (int i = tid; i < 1024; i += 256) p[i] = make_float4(0.f, 0.f, 0.f, 0.f);
        }
        return;
    }
    __shared__ __align__(16) float As[16][68];
    __shared__ __align__(16) float Bs[16][68];
    const int tx = tid & 15, ty = tid >> 4;
    const int m0 = blockIdx.y * 64, n0 = blockIdx.x * 64;
    const bool doQ = (blockIdx.z == 1);
    const int lk = tid >> 4, lc = (tid & 15) * 4;
    const int lr = tid >> 2, lk4 = (tid & 3) * 4;
    float acc[4][4] = {};
    for (int k0 = 0; k0 < 256; k0 += 16) {
        float4 av, bv4;
        if (doQ) {
            av = *(const float4*)&wq[(long long)(k0 + lk) * 512 + m0 + lc];
            bv4 = *(const float4*)&wk[(long long)(k0 + lk) * 512 + n0 + lc];
        } else {
            av = *(const float4*)&wo[(long long)(m0 + lr) * 256 + k0 + lk4];
            bv4 = *(const float4*)&wv[(long long)(k0 + lk) * 512 + n0 + lc];
        }
        __syncthreads();
        if (doQ) {
            *(float4*)&As[lk][lc] = av;
        } else {
            As[lk4 + 0][lr] = av.x; As[lk4 + 1][lr] = av.y;
            As[lk4 + 2][lr] = av.z; As[lk4 + 3][lr] = av.w;
        }
        *(float4*)&Bs[lk][lc] = bv4;
        __syncthreads();
#pragma unroll
        for (int kk = 0; kk < 16; ++kk) {
            float a[4], b[4];
#pragma unroll
            for (int i = 0; i < 4; ++i) { a[i] = As[kk][ty * 4 + i]; b[i] = Bs[kk][tx * 4 + i]; }
#pragma unroll
            for (int i = 0; i < 4; ++i)
#pragma unroll
                for (int j = 0; j < 4; ++j) acc[i][j] = fmaf(a[i], b[j], acc[i][j]);
        }
    }
    const int mo = m0 + ty * 4, no = n0 + tx * 4;
    if (doQ) {
#pragma unroll
        for (int i = 0; i < 4; ++i)
#pragma unroll
            for (int j = 0; j < 4; ++j)
                Qtb[(long long)(mo + i) * 512 + no + j] = __float2bfloat16(acc[i][j]);
    } else {
#pragma unroll
        for (int i = 0; i < 4; ++i)
#pragma unroll
            for (int j = 0; j < 4; ++j) {
                __hip_bfloat16 v = __float2bfloat16(acc[i][j]);
                Pdb[(long long)(mo + i) * 1024 + no + j] = v;
                Pdb[(long long)(mo + i) * 1024 + no + j + 512] = v;
            }
    }
}

// x [b][512][3136] fp32 -> xT [b][3200][512] bf16 (pad rows zero)
//                        + xnp [b][512][3200] bf16 (pad cols zero)
//                        + s[b][c] += rowsums (atomic)
__global__ __launch_bounds__(256)
void transpose_conv(const float* __restrict__ x, __hip_bfloat16* __restrict__ xT,
                    __hip_bfloat16* __restrict__ xnp, float* __restrict__ s)
{
    __shared__ float t[64][65];
    const int b = blockIdx.z;
    const int n0 = blockIdx.x * 64, c0 = blockIdx.y * 64;
    const int tid = threadIdx.x;
    const int nch = tid & 7;      // 8-wide chunk index
    const int cr  = tid >> 3;     // 0..31 row-within-pass
    __hip_bfloat16* xTo = xT + (long long)b * 3200 * 512;
    __hip_bfloat16* xno = xnp + (long long)b * 512 * 3200;

    if (n0 >= 3136) {             // pad tile
        bh8 z8;
#pragma unroll
        for (int k = 0; k < 8; ++k) z8.h[k] = __float2bfloat16(0.f);
#pragma unroll
        for (int pass = 0; pass < 2; ++pass) {
            int rr = cr + 32 * pass;
            *(bh8*)&xno[(long long)(c0 + rr) * 3200 + n0 + nch * 8] = z8;
            *(bh8*)&xTo[(long long)(n0 + rr) * 512 + c0 + nch * 8] = z8;
        }
        return;
    }
    const float* xb = x + (long long)b * 512 * 3136;
#pragma unroll
    for (int pass = 0; pass < 2; ++pass) {
        const int cl = cr + 32 * pass;
        const int c = c0 + cl;
        const float* xr = xb + (long long)c * 3136 + n0 + nch * 8;
        float4 v0 = *(const float4*)xr;
        float4 v1 = *(const float4*)(xr + 4);
        bh8 o;
        o.h[0] = __float2bfloat16(v0.x); o.h[1] = __float2bfloat16(v0.y);
        o.h[2] = __float2bfloat16(v0.z); o.h[3] = __float2bfloat16(v0.w);
        o.h[4] = __float2bfloat16(v1.x); o.h[5] = __float2bfloat16(v1.y);
        o.h[6] = __float2bfloat16(v1.z); o.h[7] = __float2bfloat16(v1.w);
        *(bh8*)&xno[(long long)c * 3200 + n0 + nch * 8] = o;
        const int nl = nch * 8;
        t[nl + 0][cl] = v0.x; t[nl + 1][cl] = v0.y;
        t[nl + 2][cl] = v0.z; t[nl + 3][cl] = v0.w;
        t[nl + 4][cl] = v1.x; t[nl + 5][cl] = v1.y;
        t[nl + 6][cl] = v1.z; t[nl + 7][cl] = v1.w;
        float rs = v0.x + v0.y + v0.z + v0.w + v1.x + v1.y + v1.z + v1.w;
        rs += __shfl_xor(rs, 1, 8);
        rs += __shfl_xor(rs, 2, 8);
        rs += __shfl_xor(rs, 4, 8);
        if (nch == 0) atomicAdd(&s[b * 512 + c], rs);
    }
    __syncthreads();
#pragma unroll
    for (int pass = 0; pass < 2; ++pass) {
        const int nl = cr + 32 * pass;
        const int cc = nch * 8;
        bh8 o;
#pragma unroll
        for (int k = 0; k < 8; ++k) o.h[k] = __float2bfloat16(t[nl][cc + k]);
        *(bh8*)&xTo[(long long)(n0 + nl) * 512 + c0 + cc] = o;
    }
}

// Wave-per-output: ps = P·s, sq = Qt·s, a2 = [T·w + u(s·w) + ps·κ]/N + uκ + bo.
__global__ __launch_bounds__(256)
void vec2_kernel(const __hip_bfloat16* __restrict__ T, const __hip_bfloat16* __restrict__ Pdb,
                 const __hip_bfloat16* __restrict__ Qtb, const float* __restrict__ s,
                 const float* __restrict__ u, const float* __restrict__ w,
                 const float* __restrict__ kap, const float* __restrict__ bo,
                 float* __restrict__ ps, float* __restrict__ sq, float* __restrict__ a2)
{
    const int idx = blockIdx.x * 4 + (threadIdx.x >> 6);   // b*512+c
    const int lane = threadIdx.x & 63;
    const int b = idx >> 9, c = idx & 511;
    const int j0 = lane * 8;
    const float* sb = s + b * 512;
    float4 s0 = *(const float4*)&sb[j0], s1 = *(const float4*)&sb[j0 + 4];
    float4 w0 = *(const float4*)&w[j0],  w1 = *(const float4*)&w[j0 + 4];
    bf16x8 pv = *(const bf16x8*)&Pdb[(long long)c * 1024 + j0];
    bf16x8 qv = *(const bf16x8*)&Qtb[(long long)c * 512 + j0];
    bf16x8 tv = *(const bf16x8*)&T[(long long)b * 262144 + (long long)c * 512 + j0];
    float sj[8] = {s0.x, s0.y, s0.z, s0.w, s1.x, s1.y, s1.z, s1.w};
    float wj[8] = {w0.x, w0.y, w0.z, w0.w, w1.x, w1.y, w1.z, w1.w};
    float aps = 0.f, asq = 0.f, atw = 0.f, asw = 0.f;
#pragma unroll
    for (int t = 0; t < 8; ++t) {
        aps = fmaf((float)pv[t], sj[t], aps);
        asq = fmaf((float)qv[t], sj[t], asq);
        atw = fmaf((float)tv[t], wj[t], atw);
        asw = fmaf(sj[t], wj[t], asw);
    }
#pragma unroll
    for (int m = 1; m < 64; m <<= 1) {
        aps += __shfl_xor(aps, m);
        asq += __shfl_xor(asq, m);
        atw += __shfl_xor(atw, m);
        asw += __shfl_xor(asw, m);
    }
    if (lane == 0) {
        ps[idx] = aps; sq[idx] = asq;
        float kp = *kap;
        a2[idx] = (atw + u[c] * asw + aps * kp) * (1.f / 3136.f) + u[c] * kp + bo[c];
    }
}

#define SWZ64(row) ((row) & 7)

// G GEMM with symmetric mirroring. 64x64 tile, BK=64, operands = xnp (both).
// Grid: x = batch + 8*ks (XCD affinity), y = triangular pair index (36).
// Double-buffered 2-phase K-loop: stage(kt+1) -> compute(kt) -> syncthreads.
__global__ __launch_bounds__(256)
void mfma_g(const __hip_bfloat16* __restrict__ A, long long sA, int lda,
            __hip_bfloat16* __restrict__ C, long long sC, int ldc,
            int kLen)
{
    constexpr int BKT = 64;
    constexpr int CPR = BKT / 8;
    constexpr int NC = 64 * CPR / 256;
    constexpr int LSZ = 64 * BKT;
    __shared__ __hip_bfloat16 As[2 * LSZ];
    __shared__ __hip_bfloat16 Bs[2 * LSZ];
    const int tid = threadIdx.x;
    const int lane = tid & 63;
    const int w = tid >> 6;
    const int wm = (w >> 1) << 5;
    const int wn = (w & 1) << 5;
    const int ln = lane & 15;
    const int hi = lane >> 4;
    const int bx = blockIdx.x;
    const int batch = bx & 7, ks = bx >> 3;
    int p = blockIdx.y, mt = 0;
    while (p >= 8 - mt) { p -= 8 - mt; ++mt; }
    const int nt = mt + p;
    const int m0 = mt << 6, n0 = nt << 6;
    const long long k0 = (long long)ks * kLen;

    const __hip_bfloat16* gA[NC];
    const __hip_bfloat16* gB[NC];
#pragma unroll
    for (int q0 = 0; q0 < NC; ++q0) {
        int q = tid + 256 * q0;
        int row = q / CPR;
        int c = (q % CPR) ^ SWZ64(row);
        gA[q0] = A + batch * sA + (long long)(m0 + row) * lda + k0 + c * 8;
        gB[q0] = A + batch * sA + (long long)(n0 + row) * lda + k0 + c * 8;
    }
    floatx4 acc[2][2] = {};
    const int nK = kLen / BKT;

    // prologue: stage tile 0 into buffer 0
#pragma unroll
    for (int q0 = 0; q0 < NC; ++q0) {
        load_lds16(gA[q0], As + (tid + 256 * q0) * 8);
        load_lds16(gB[q0], Bs + (tid + 256 * q0) * 8);
        gA[q0] += BKT; gB[q0] += BKT;
    }
    __syncthreads();

    int cur = 0;
    for (int kt = 0; kt < nK; ++kt) {
        if (kt + 1 < nK) {
            const int off = (cur ^ 1) * LSZ;
#pragma unroll
            for (int q0 = 0; q0 < NC; ++q0) {
                load_lds16(gA[q0], As + off + (tid + 256 * q0) * 8);
                load_lds16(gB[q0], Bs + off + (tid + 256 * q0) * 8);
                gA[q0] += BKT; gB[q0] += BKT;
            }
        }
        const __hip_bfloat16* Ac = As + cur * LSZ;
        const __hip_bfloat16* Bc = Bs + cur * LSZ;
#pragma unroll
        for (int kk = 0; kk < BKT / 32; ++kk) {
            const int cidx = kk * 4 + hi;
            bf16x8 af[2], bfr[2];
#pragma unroll
            for (int i = 0; i < 2; ++i) {
                int row = wm + i * 16 + ln;
                af[i] = *(const bf16x8*)(Ac + row * BKT + ((cidx ^ SWZ64(row)) << 3));
            }
#pragma unroll
            for (int j = 0; j < 2; ++j) {
                int row = wn + j * 16 + ln;
                bfr[j] = *(const bf16x8*)(Bc + row * BKT + ((cidx ^ SWZ64(row)) << 3));
            }
#pragma unroll
            for (int i = 0; i < 2; ++i)
#pragma unroll
                for (int j = 0; j < 2; ++j)
                    acc[i][j] = __builtin_amdgcn_mfma_f32_16x16x32_bf16(af[i], bfr[j], acc[i][j], 0, 0, 0);
        }
        if (kt + 1 < nK) {
            __syncthreads();   // drains vmcnt (next stage landed) + lgkmcnt (buf consumed)
            cur ^= 1;
        }
    }

    // C/D layout: col = lane&15, row = (lane>>4)*4 + r  [m89-verified]
    __hip_bfloat16* Cb = C + batch * sC + ks * 512;
#pragma unroll
    for (int i = 0; i < 2; ++i) {
        int mb = m0 + wm + i * 16 + hi * 4;
#pragma unroll
        for (int j = 0; j < 2; ++j) {
            int nl = n0 + wn + j * 16 + ln;
            bh4 mv;
            mv.x = __float2bfloat16(acc[i][j][0]);
            mv.y = __float2bfloat16(acc[i][j][1]);
            mv.z = __float2bfloat16(acc[i][j][2]);
            mv.w = __float2bfloat16(acc[i][j][3]);
            Cb[(long long)(mb + 0) * ldc + nl] = mv.x;
            Cb[(long long)(mb + 1) * ldc + nl] = mv.y;
            Cb[(long long)(mb + 2) * ldc + nl] = mv.z;
            Cb[(long long)(mb + 3) * ldc + nl] = mv.w;
            if (mt != nt)
                *(bh4*)&Cb[(long long)nl * ldc + mb] = mv;   // mirrored tile
        }
    }
}

// Small MFMA GEMM, 64x64 tile, BK=64, operands K-contiguous.
// MODE 5: plain bf16 store.
// MODE 6: bf16 store of (acc + u[m]·sq[b][n] + ps[b][m]·r[n])/N + u[m]·r[n].
// Double-buffered 2-phase K-loop.
template<int MODE>
__global__ __launch_bounds__(256)
void mfma_sm(const __hip_bfloat16* __restrict__ A, long long sA, int lda,
             const __hip_bfloat16* __restrict__ B, long long sB, int ldb,
             __hip_bfloat16* __restrict__ C, long long sC, int ldc,
             const float* __restrict__ pu, const float* __restrict__ pr,
             const float* __restrict__ pps, const float* __restrict__ psq,
             int kLen)
{
    constexpr int BKT = 64;
    constexpr int CPR = BKT / 8;
    constexpr int NC = 64 * CPR / 256;
    constexpr int LSZ = 64 * BKT;
    __shared__ __hip_bfloat16 As[2 * LSZ];
    __shared__ __hip_bfloat16 Bs[2 * LSZ];
    const int tid = threadIdx.x;
    const int lane = tid & 63;
    const int w = tid >> 6;
    const int wm = (w >> 1) << 5;
    const int wn = (w & 1) << 5;
    const int ln = lane & 15;
    const int hi = lane >> 4;
    const int batch = blockIdx.x;
    const int m0 = blockIdx.z << 6;
    const int n0 = blockIdx.y << 6;

    const __hip_bfloat16* gA[NC];
    const __hip_bfloat16* gB[NC];
#pragma unroll
    for (int q0 = 0; q0 < NC; ++q0) {
        int q = tid + 256 * q0;
        int row = q / CPR;
        int c = (q % CPR) ^ SWZ64(row);
        gA[q0] = A + batch * sA + (long long)(m0 + row) * lda + c * 8;
        gB[q0] = B + batch * sB + (long long)(n0 + row) * ldb + c * 8;
    }
    floatx4 acc[2][2] = {};
    const int nK = kLen / BKT;

#pragma unroll
    for (int q0 = 0; q0 < NC; ++q0) {
        load_lds16(gA[q0], As + (tid + 256 * q0) * 8);
        load_lds16(gB[q0], Bs + (tid + 256 * q0) * 8);
        gA[q0] += BKT; gB[q0] += BKT;
    }
    __syncthreads();

    int cur = 0;
    for (int kt = 0; kt < nK; ++kt) {
        if (kt + 1 < nK) {
            const int off = (cur ^ 1) * LSZ;
#pragma unroll
            for (int q0 = 0; q0 < NC; ++q0) {
                load_lds16(gA[q0], As + off + (tid + 256 * q0) * 8);
                load_lds16(gB[q0], Bs + off + (tid + 256 * q0) * 8);
                gA[q0] += BKT; gB[q0] += BKT;
            }
        }
        const __hip_bfloat16* Ac = As + cur * LSZ;
        const __hip_bfloat16* Bc = Bs + cur * LSZ;
#pragma unroll
        for (int kk = 0; kk < BKT / 32; ++kk) {
            const int cidx = kk * 4 + hi;
            bf16x8 af[2], bfr[2];
#pragma unroll
            for (int i = 0; i < 2; ++i) {
                int row = wm + i * 16 + ln;
                af[i] = *(const bf16x8*)(Ac + row * BKT + ((cidx ^ SWZ64(row)) << 3));
            }
#pragma unroll
            for (int j = 0; j < 2; ++j) {
                int row = wn + j * 16 + ln;
                bfr[j] = *(const bf16x8*)(Bc + row * BKT + ((cidx ^ SWZ64(row)) << 3));
            }
#pragma unroll
            for (int i = 0; i < 2; ++i)
#pragma unroll
                for (int j = 0; j < 2; ++j)
                    acc[i][j] = __builtin_amdgcn_mfma_f32_16x16x32_bf16(af[i], bfr[j], acc[i][j], 0, 0, 0);
        }
        if (kt + 1 < nK) {
            __syncthreads();
            cur ^= 1;
        }
    }

    __hip_bfloat16* Cb = C + batch * sC;
#pragma unroll
    for (int i = 0; i < 2; ++i) {
        int mb = m0 + wm + i * 16 + hi * 4;
#pragma unroll
        for (int r = 0; r < 4; ++r) {
#pragma unroll
            for (int j = 0; j < 2; ++j) {
                int nl = n0 + wn + j * 16 + ln;
                float v = acc[i][j][r];
                if (MODE == 6) {
                    float uu = pu[mb + r], rr = pr[nl];
                    v = (v + uu * psq[batch * 512 + nl] + pps[batch * 512 + mb + r] * rr)
                        * (1.f / 3136.f) + uu * rr;
                }
                Cb[(long long)(mb + r) * ldc + nl] = __float2bfloat16(v);
            }
        }
    }
}

// Final MFMA GEMM: 128(M)x128(N) tile, 4 waves in 2x2 (64x64 each), BK=64,
// single-buffered 2-barrier m97-style loop (proven structure; guide tile-space
// 64²=343 vs 128²=912 TF). 32KB LDS -> 5 blocks/CU ceiling; grid 800 = 3.1/CU.
// Residual x + bias read in the epilogue (overlaps across co-resident blocks).
__global__ __launch_bounds__(256)
void mfma128(const __hip_bfloat16* __restrict__ A, long long sA, int lda,
             const __hip_bfloat16* __restrict__ B, long long sB, int ldb,
             float* __restrict__ C, long long sC, int ldc,
             const float* __restrict__ bias, int sBias,
             const float* __restrict__ xres, long long sX,
             int kLen, int Nreal)
{
    constexpr int BKT = 64;
    constexpr int CPR = BKT / 8;             // 8 chunks of 16B per row
    constexpr int NA = 128 * CPR / 256;      // 4 loads/thread for A tile
    constexpr int NB = 128 * CPR / 256;      // 4 loads/thread for B tile
    __shared__ __hip_bfloat16 As[128 * BKT];
    __shared__ __hip_bfloat16 Bs[128 * BKT];
    const int tid = threadIdx.x;
    const int lane = tid & 63;
    const int w = tid >> 6;
    const int wm = (w >> 1) << 6;            // wave row offset: 0 / 64
    const int wn = (w & 1) << 6;             // wave col offset: 0 / 64
    const int ln = lane & 15;
    const int hi = lane >> 4;
    const int batch = blockIdx.x;
    const int m0 = blockIdx.z << 7;
    const int n0 = blockIdx.y << 7;

    const __hip_bfloat16* gA[NA];
    const __hip_bfloat16* gB[NB];
#pragma unroll
    for (int q0 = 0; q0 < NA; ++q0) {
        int q = tid + 256 * q0;
        int row = q / CPR;
        int c = (q % CPR) ^ SWZ64(row);
        gA[q0] = A + batch * sA + (long long)(m0 + row) * lda + c * 8;
        gB[q0] = B + batch * sB + (long long)(n0 + row) * ldb + c * 8;
    }

    floatx4 acc[4][4] = {};
    const int nK = kLen / BKT;
    for (int kt = 0; kt < nK; ++kt) {
#pragma unroll
        for (int q0 = 0; q0 < NA; ++q0) {
            load_lds16(gA[q0], As + (tid + 256 * q0) * 8);
            load_lds16(gB[q0], Bs + (tid + 256 * q0) * 8);
            gA[q0] += BKT; gB[q0] += BKT;
        }
        __syncthreads();
#pragma unroll
        for (int kk = 0; kk < BKT / 32; ++kk) {
            const int cidx = kk * 4 + hi;
            bf16x8 af[4], bfr[4];
#pragma unroll
            for (int i = 0; i < 4; ++i) {
                int row = wm + i * 16 + ln;
                af[i] = *(const bf16x8*)(As + row * BKT + ((cidx ^ SWZ64(row)) << 3));
            }
#pragma unroll
            for (int j = 0; j < 4; ++j) {
                int row = wn + j * 16 + ln;
                bfr[j] = *(const bf16x8*)(Bs + row * BKT + ((cidx ^ SWZ64(row)) << 3));
            }
#pragma unroll
            for (int i = 0; i < 4; ++i)
#pragma unroll
                for (int j = 0; j < 4; ++j)
                    acc[i][j] = __builtin_amdgcn_mfma_f32_16x16x32_bf16(af[i], bfr[j], acc[i][j], 0, 0, 0);
        }
        __syncthreads();
    }

    // epilogue: out = acc + bias[m] + x[m][n]; C/D layout col=ln, row=hi*4+r
    float* Cb = C + batch * sC;
    const float* xb = xres + batch * sX;
#pragma unroll
    for (int i = 0; i < 4; ++i) {
        int mb = m0 + wm + i * 16 + hi * 4;
#pragma unroll
        for (int r = 0; r < 4; ++r) {
            float bb = bias[batch * sBias + mb + r];
            const float* xrow = xb + (long long)(mb + r) * ldc;
            float* crow = Cb + (long long)(mb + r) * ldc;
#pragma unroll
            for (int j = 0; j < 4; ++j) {
                int nl = n0 + wn + j * 16 + ln;
                if (nl < Nreal) {
                    crow[nl] = acc[i][j][r] + bb + xrow[nl];
                }
            }
        }
    }
}

extern "C" void kernel_launch(void* const* d_in, const int* in_sizes, int n_in,
                              void* d_out, int out_size, void* d_ws, size_t ws_size,
                              hipStream_t stream)
{
    const float* x  = (const float*)d_in[0];
    const float* wq = (const float*)d_in[1];
    const float* bq = (const float*)d_in[2];
    const float* wk = (const float*)d_in[3];
    const float* bk = (const float*)d_in[4];
    const float* wv = (const float*)d_in[5];
    const float* bv = (const float*)d_in[6];
    const float* wo = (const float*)d_in[7];
    const float* bo = (const float*)d_in[8];
    float* out = (float*)d_out;

    const int N = 3136;
    const long long xs = 512LL * N;               // 1,605,632
    const long long xs2 = 512LL * 3200;           // xnp per-batch stride

    // d_out scratch (51.4 MB), all dead before the final GEMM writes out:
    char* ob = (char*)d_out;
    __hip_bfloat16* xnp = (__hip_bfloat16*)ob;                 // @0: 26,214,400 (dead after G)
    __hip_bfloat16* Gp2 = (__hip_bfloat16*)(ob + 26214400);    // 8x512x1024 bf16 = 8,388,608
    __hip_bfloat16* Tb  = (__hip_bfloat16*)(ob + 34603008);    // 8x512x512 bf16 = 4,194,304

    // ws (~32.05 MB). Final GEMM reads only ws + x.
    char* wsb = (char*)d_ws;
    __hip_bfloat16* xT  = (__hip_bfloat16*)wsb;                // 26,214,400
    __hip_bfloat16* A2b = (__hip_bfloat16*)(wsb + 26214400);   //  4,194,304
    __hip_bfloat16* Pdb = (__hip_bfloat16*)(wsb + 30408704);   //  1,048,576
    __hip_bfloat16* Qtb = (__hip_bfloat16*)(wsb + 31457280);   //    524,288
    float* sv  = (float*)(wsb + 31981568);                     //     16,384
    float* u_  = (float*)(wsb + 31997952);                     //      2,048
    float* r_  = (float*)(wsb + 32000000);                     //      2,048
    float* w_  = (float*)(wsb + 32002048);                     //      2,048
    float* kap = (float*)(wsb + 32004096);                     //         16
    float* ps  = (float*)(wsb + 32004112);                     //     16,384
    float* sq  = (float*)(wsb + 32020496);                     //     16,384
    float* a2v = (float*)(wsb + 32036880);                     //     16,384

    // 1) fused data-independent precompute (P/Qt/u/r/w/kap + zero s)
    prep_all<<<dim3(8, 8, 3), 256, 0, stream>>>(wo, wv, wq, wk, bq, bk, bv,
                                                Pdb, Qtb, u_, r_, w_, kap, sv);

    // 2) xT + xnp + s (16B stores)
    transpose_conv<<<dim3(50, 8, 8), 256, 0, stream>>>(x, xT, xnp, sv);

    // 3) Gp2 = partials of X·X^T  (split-K=2, K=1600, BK=64), symmetric:
    //    36 upper-tri tile pairs x 16 (batch,ks) = 576 blocks, mirror on store
    mfma_g<<<dim3(16, 36), 256, 0, stream>>>(
        xnp, xs2, 3200, Gp2, 524288, 1024, 1600);

    // 4) T = Pd·Gp2  (K=1024 folds the split-K reduce)
    mfma_sm<5><<<dim3(8, 8, 8), 256, 0, stream>>>(
        Pdb, 0, 1024, Gp2, 524288, 1024, Tb, 262144, 512,
        nullptr, nullptr, nullptr, nullptr, 1024);

    // 5) ps = P·s, sq = Qt·s, a2 = [T·w + u(s·w) + ps·κ]/N + uκ + bo
    vec2_kernel<<<1024, 256, 0, stream>>>(Tb, Pdb, Qtb, sv, u_, w_, kap, bo, ps, sq, a2v);

    // 6) A2 = [T·Q + u·sq^T + ps·r^T]/N + u·r^T  -> bf16
    mfma_sm<6><<<dim3(8, 8, 8), 256, 0, stream>>>(
        Tb, 262144, 512, Qtb, 0, 512, A2b, 262144, 512,
        u_, r_, ps, sq, 512);

    // 7) out = A2·X + a2 + x   (M=512, N=3136, K=512), 128x128 tiles
    mfma128<<<dim3(8, 25, 4), 256, 0, stream>>>(
        A2b, 262144, 512, xT, 3200LL * 512, 512,
        out, xs, N, a2v, 512, x, xs, 512, N);
}

// Round 4
// 228.641 us; speedup vs baseline: 1.2449x; 1.0494x over previous
//
#include <hip/hip_runtime.h>
#include <hip/hip_bf16.h>

// DotProductNonLocalBlock: B=8, C=512, N=3136 (pad 3200), E=256.
// No softmax => fully associative. Factored with DATA-INDEPENDENT
// P = wo·wv, Qt = wq^T·wk, u = wo·bv, r = bk^T·wq, w = Wk^T·bq, κ = bk·bq:
//   G  = X·X^T   [bf16 MFMA, split-K=2 col-interleaved partials, SYMMETRIC]
//   T  = Pd·Gp2 (K=1024 folds the reduce)
//   A2 = [T·Q + u·(Qt s)^T + (P s)·r^T]/N + u·r^T
//   a2 = [T·w + u·(s·w) + (P s)·κ]/N + u·κ + bo
//   Out = A2·X + a2 + X
// Batch in blockIdx.x on all MFMA grids (XCD affinity; per-batch panels fit 4MB L2).
// LEDGER final GEMM: 64x128 single-buf = 47.5us (BEST) | dbuf-drain = 52.2 |
//   128x128 single-buf = 59.3 | zero-LDS = 107. Kept: R0 exact.
// Round 10: mfma_g/mfma_sm (dbuf, 32KB, occupancy-neutral per R1) switch from
//   __syncthreads (vmcnt(0) drain per K-step — the measured latency tax) to
//   counted s_waitcnt vmcnt(4) + raw s_barrier (T3/T4-min, m135/m218 semantics):
//   next tile's 4 loads stay in flight across the barrier. Race audit:
//   (1) vmcnt(4)+barrier -> buf[cur] loads landed on all threads (FIFO retire);
//   (2) trailing barrier -> no wave restages buf[cur] before all ds_reads of it
//       are consumed (reads consumed by MFMA before barrier in program order).

typedef __attribute__((ext_vector_type(8))) __bf16 bf16x8;
typedef __attribute__((ext_vector_type(4))) float floatx4;

struct __align__(8) bh4 { __hip_bfloat16 x, y, z, w; };
struct __align__(16) bh8 { __hip_bfloat16 h[8]; };

__device__ __forceinline__ void load_lds16(const void* g, void* l) {
    __builtin_amdgcn_global_load_lds((const __attribute__((address_space(1))) void*)g,
                                     (__attribute__((address_space(3))) void*)l, 16, 0, 0);
}

// ---- fused data-independent precompute ----
// z=0: Pd=[P|P] (bf16 512x1024, P=wo·wv).  z=1: Qt (bf16 512x512, wq^T·wk).
// z=2: blocks 0,1 -> u/r/w/kap vectors; block 2 -> zero s accumulator.
__global__ __launch_bounds__(256)
void prep_all(const float* __restrict__ wo, const float* __restrict__ wv,
              const float* __restrict__ wq, const float* __restrict__ wk,
              const float* __restrict__ bq, const float* __restrict__ bk,
              const float* __restrict__ bv,
              __hip_bfloat16* __restrict__ Pdb, __hip_bfloat16* __restrict__ Qtb,
              float* __restrict__ u, float* __restrict__ r, float* __restrict__ w,
              float* __restrict__ kap, float* __restrict__ sv)
{
    const int tid = threadIdx.x;
    if (blockIdx.z == 2) {
        int blk = blockIdx.y * 8 + blockIdx.x;
        if (blk < 2) {
            int c = blk * 256 + tid;
            float su = 0.f, sr = 0.f, sw = 0.f;
            for (int e = 0; e < 256; ++e) {
                su = fmaf(wo[(long long)c * 256 + e], bv[e], su);
                sr = fmaf(bk[e], wq[(long long)e * 512 + c], sr);
                sw = fmaf(wk[(long long)e * 512 + c], bq[e], sw);
            }
            u[c] = su; r[c] = sr; w[c] = sw;
            if (c == 0) {
                float k2 = 0.f;
                for (int e = 0; e < 256; ++e) k2 = fmaf(bk[e], bq[e], k2);
                *kap = k2;
            }
        } else if (blk == 2) {
            float4* p = (float4*)sv;
            for (int i = tid; i < 1024; i += 256) p[i] = make_float4(0.f, 0.f, 0.f, 0.f);
        }
        return;
    }
    __shared__ __align__(16) float As[16][68];
    __shared__ __align__(16) float Bs[16][68];
    const int tx = tid & 15, ty = tid >> 4;
    const int m0 = blockIdx.y * 64, n0 = blockIdx.x * 64;
    const bool doQ = (blockIdx.z == 1);
    const int lk = tid >> 4, lc = (tid & 15) * 4;
    const int lr = tid >> 2, lk4 = (tid & 3) * 4;
    float acc[4][4] = {};
    for (int k0 = 0; k0 < 256; k0 += 16) {
        float4 av, bv4;
        if (doQ) {
            av = *(const float4*)&wq[(long long)(k0 + lk) * 512 + m0 + lc];
            bv4 = *(const float4*)&wk[(long long)(k0 + lk) * 512 + n0 + lc];
        } else {
            av = *(const float4*)&wo[(long long)(m0 + lr) * 256 + k0 + lk4];
            bv4 = *(const float4*)&wv[(long long)(k0 + lk) * 512 + n0 + lc];
        }
        __syncthreads();
        if (doQ) {
            *(float4*)&As[lk][lc] = av;
        } else {
            As[lk4 + 0][lr] = av.x; As[lk4 + 1][lr] = av.y;
            As[lk4 + 2][lr] = av.z; As[lk4 + 3][lr] = av.w;
        }
        *(float4*)&Bs[lk][lc] = bv4;
        __syncthreads();
#pragma unroll
        for (int kk = 0; kk < 16; ++kk) {
            float a[4], b[4];
#pragma unroll
            for (int i = 0; i < 4; ++i) { a[i] = As[kk][ty * 4 + i]; b[i] = Bs[kk][tx * 4 + i]; }
#pragma unroll
            for (int i = 0; i < 4; ++i)
#pragma unroll
                for (int j = 0; j < 4; ++j) acc[i][j] = fmaf(a[i], b[j], acc[i][j]);
        }
    }
    const int mo = m0 + ty * 4, no = n0 + tx * 4;
    if (doQ) {
#pragma unroll
        for (int i = 0; i < 4; ++i)
#pragma unroll
            for (int j = 0; j < 4; ++j)
                Qtb[(long long)(mo + i) * 512 + no + j] = __float2bfloat16(acc[i][j]);
    } else {
#pragma unroll
        for (int i = 0; i < 4; ++i)
#pragma unroll
            for (int j = 0; j < 4; ++j) {
                __hip_bfloat16 v = __float2bfloat16(acc[i][j]);
                Pdb[(long long)(mo + i) * 1024 + no + j] = v;
                Pdb[(long long)(mo + i) * 1024 + no + j + 512] = v;
            }
    }
}

// x [b][512][3136] fp32 -> xT [b][3200][512] bf16 (pad rows zero)
//                        + xnp [b][512][3200] bf16 (pad cols zero)
//                        + s[b][c] += rowsums (atomic)
__global__ __launch_bounds__(256)
void transpose_conv(const float* __restrict__ x, __hip_bfloat16* __restrict__ xT,
                    __hip_bfloat16* __restrict__ xnp, float* __restrict__ s)
{
    __shared__ float t[64][65];
    const int b = blockIdx.z;
    const int n0 = blockIdx.x * 64, c0 = blockIdx.y * 64;
    const int tid = threadIdx.x;
    const int nch = tid & 7;      // 8-wide chunk index
    const int cr  = tid >> 3;     // 0..31 row-within-pass
    __hip_bfloat16* xTo = xT + (long long)b * 3200 * 512;
    __hip_bfloat16* xno = xnp + (long long)b * 512 * 3200;

    if (n0 >= 3136) {             // pad tile
        bh8 z8;
#pragma unroll
        for (int k = 0; k < 8; ++k) z8.h[k] = __float2bfloat16(0.f);
#pragma unroll
        for (int pass = 0; pass < 2; ++pass) {
            int rr = cr + 32 * pass;
            *(bh8*)&xno[(long long)(c0 + rr) * 3200 + n0 + nch * 8] = z8;
            *(bh8*)&xTo[(long long)(n0 + rr) * 512 + c0 + nch * 8] = z8;
        }
        return;
    }
    const float* xb = x + (long long)b * 512 * 3136;
#pragma unroll
    for (int pass = 0; pass < 2; ++pass) {
        const int cl = cr + 32 * pass;
        const int c = c0 + cl;
        const float* xr = xb + (long long)c * 3136 + n0 + nch * 8;
        float4 v0 = *(const float4*)xr;
        float4 v1 = *(const float4*)(xr + 4);
        bh8 o;
        o.h[0] = __float2bfloat16(v0.x); o.h[1] = __float2bfloat16(v0.y);
        o.h[2] = __float2bfloat16(v0.z); o.h[3] = __float2bfloat16(v0.w);
        o.h[4] = __float2bfloat16(v1.x); o.h[5] = __float2bfloat16(v1.y);
        o.h[6] = __float2bfloat16(v1.z); o.h[7] = __float2bfloat16(v1.w);
        *(bh8*)&xno[(long long)c * 3200 + n0 + nch * 8] = o;
        const int nl = nch * 8;
        t[nl + 0][cl] = v0.x; t[nl + 1][cl] = v0.y;
        t[nl + 2][cl] = v0.z; t[nl + 3][cl] = v0.w;
        t[nl + 4][cl] = v1.x; t[nl + 5][cl] = v1.y;
        t[nl + 6][cl] = v1.z; t[nl + 7][cl] = v1.w;
        float rs = v0.x + v0.y + v0.z + v0.w + v1.x + v1.y + v1.z + v1.w;
        rs += __shfl_xor(rs, 1, 8);
        rs += __shfl_xor(rs, 2, 8);
        rs += __shfl_xor(rs, 4, 8);
        if (nch == 0) atomicAdd(&s[b * 512 + c], rs);
    }
    __syncthreads();
#pragma unroll
    for (int pass = 0; pass < 2; ++pass) {
        const int nl = cr + 32 * pass;
        const int cc = nch * 8;
        bh8 o;
#pragma unroll
        for (int k = 0; k < 8; ++k) o.h[k] = __float2bfloat16(t[nl][cc + k]);
        *(bh8*)&xTo[(long long)(n0 + nl) * 512 + c0 + cc] = o;
    }
}

// Wave-per-output: ps = P·s, sq = Qt·s, a2 = [T·w + u(s·w) + ps·κ]/N + uκ + bo.
__global__ __launch_bounds__(256)
void vec2_kernel(const __hip_bfloat16* __restrict__ T, const __hip_bfloat16* __restrict__ Pdb,
                 const __hip_bfloat16* __restrict__ Qtb, const float* __restrict__ s,
                 const float* __restrict__ u, const float* __restrict__ w,
                 const float* __restrict__ kap, const float* __restrict__ bo,
                 float* __restrict__ ps, float* __restrict__ sq, float* __restrict__ a2)
{
    const int idx = blockIdx.x * 4 + (threadIdx.x >> 6);   // b*512+c
    const int lane = threadIdx.x & 63;
    const int b = idx >> 9, c = idx & 511;
    const int j0 = lane * 8;
    const float* sb = s + b * 512;
    float4 s0 = *(const float4*)&sb[j0], s1 = *(const float4*)&sb[j0 + 4];
    float4 w0 = *(const float4*)&w[j0],  w1 = *(const float4*)&w[j0 + 4];
    bf16x8 pv = *(const bf16x8*)&Pdb[(long long)c * 1024 + j0];
    bf16x8 qv = *(const bf16x8*)&Qtb[(long long)c * 512 + j0];
    bf16x8 tv = *(const bf16x8*)&T[(long long)b * 262144 + (long long)c * 512 + j0];
    float sj[8] = {s0.x, s0.y, s0.z, s0.w, s1.x, s1.y, s1.z, s1.w};
    float wj[8] = {w0.x, w0.y, w0.z, w0.w, w1.x, w1.y, w1.z, w1.w};
    float aps = 0.f, asq = 0.f, atw = 0.f, asw = 0.f;
#pragma unroll
    for (int t = 0; t < 8; ++t) {
        aps = fmaf((float)pv[t], sj[t], aps);
        asq = fmaf((float)qv[t], sj[t], asq);
        atw = fmaf((float)tv[t], wj[t], atw);
        asw = fmaf(sj[t], wj[t], asw);
    }
#pragma unroll
    for (int m = 1; m < 64; m <<= 1) {
        aps += __shfl_xor(aps, m);
        asq += __shfl_xor(asq, m);
        atw += __shfl_xor(atw, m);
        asw += __shfl_xor(asw, m);
    }
    if (lane == 0) {
        ps[idx] = aps; sq[idx] = asq;
        float kp = *kap;
        a2[idx] = (atw + u[c] * asw + aps * kp) * (1.f / 3136.f) + u[c] * kp + bo[c];
    }
}

#define SWZ64(row) ((row) & 7)

// G GEMM with symmetric mirroring. 64x64 tile, BK=64, operands = xnp (both).
// Grid: x = batch + 8*ks (XCD affinity), y = triangular pair index (36).
// Counted-vmcnt double-buffered K-loop (T3/T4-min): 4 loads/thread/stage;
// vmcnt(4) keeps the next tile's loads in flight across the barrier.
__global__ __launch_bounds__(256)
void mfma_g(const __hip_bfloat16* __restrict__ A, long long sA, int lda,
            __hip_bfloat16* __restrict__ C, long long sC, int ldc,
            int kLen)
{
    constexpr int BKT = 64;
    constexpr int CPR = BKT / 8;
    constexpr int NC = 64 * CPR / 256;
    constexpr int LSZ = 64 * BKT;
    __shared__ __hip_bfloat16 As[2 * LSZ];
    __shared__ __hip_bfloat16 Bs[2 * LSZ];
    const int tid = threadIdx.x;
    const int lane = tid & 63;
    const int w = tid >> 6;
    const int wm = (w >> 1) << 5;
    const int wn = (w & 1) << 5;
    const int ln = lane & 15;
    const int hi = lane >> 4;
    const int bx = blockIdx.x;
    const int batch = bx & 7, ks = bx >> 3;
    int p = blockIdx.y, mt = 0;
    while (p >= 8 - mt) { p -= 8 - mt; ++mt; }
    const int nt = mt + p;
    const int m0 = mt << 6, n0 = nt << 6;
    const long long k0 = (long long)ks * kLen;

    const __hip_bfloat16* gA[NC];
    const __hip_bfloat16* gB[NC];
#pragma unroll
    for (int q0 = 0; q0 < NC; ++q0) {
        int q = tid + 256 * q0;
        int row = q / CPR;
        int c = (q % CPR) ^ SWZ64(row);
        gA[q0] = A + batch * sA + (long long)(m0 + row) * lda + k0 + c * 8;
        gB[q0] = A + batch * sA + (long long)(n0 + row) * lda + k0 + c * 8;
    }
    floatx4 acc[2][2] = {};
    const int nK = kLen / BKT;

    // prologue: stage tile 0 into buffer 0 (4 loads/thread in flight)
#pragma unroll
    for (int q0 = 0; q0 < NC; ++q0) {
        load_lds16(gA[q0], As + (tid + 256 * q0) * 8);
        load_lds16(gB[q0], Bs + (tid + 256 * q0) * 8);
        gA[q0] += BKT; gB[q0] += BKT;
    }

    int cur = 0;
    for (int kt = 0; kt < nK; ++kt) {
        if (kt + 1 < nK) {
            const int off = (cur ^ 1) * LSZ;
#pragma unroll
            for (int q0 = 0; q0 < NC; ++q0) {
                load_lds16(gA[q0], As + off + (tid + 256 * q0) * 8);
                load_lds16(gB[q0], Bs + off + (tid + 256 * q0) * 8);
                gA[q0] += BKT; gB[q0] += BKT;
            }
            asm volatile("s_waitcnt vmcnt(4)" ::: "memory");   // cur tile landed; next in flight
        } else {
            asm volatile("s_waitcnt vmcnt(0)" ::: "memory");   // final tile landed
        }
        __builtin_amdgcn_s_barrier();
        const __hip_bfloat16* Ac = As + cur * LSZ;
        const __hip_bfloat16* Bc = Bs + cur * LSZ;
#pragma unroll
        for (int kk = 0; kk < BKT / 32; ++kk) {
            const int cidx = kk * 4 + hi;
            bf16x8 af[2], bfr[2];
#pragma unroll
            for (int i = 0; i < 2; ++i) {
                int row = wm + i * 16 + ln;
                af[i] = *(const bf16x8*)(Ac + row * BKT + ((cidx ^ SWZ64(row)) << 3));
            }
#pragma unroll
            for (int j = 0; j < 2; ++j) {
                int row = wn + j * 16 + ln;
                bfr[j] = *(const bf16x8*)(Bc + row * BKT + ((cidx ^ SWZ64(row)) << 3));
            }
#pragma unroll
            for (int i = 0; i < 2; ++i)
#pragma unroll
                for (int j = 0; j < 2; ++j)
                    acc[i][j] = __builtin_amdgcn_mfma_f32_16x16x32_bf16(af[i], bfr[j], acc[i][j], 0, 0, 0);
        }
        if (kt + 1 < nK) {
            __builtin_amdgcn_s_barrier();   // buf[cur] fully read -> safe to restage next iter
            cur ^= 1;
        }
    }

    // C/D layout: col = lane&15, row = (lane>>4)*4 + r  [m89-verified]
    __hip_bfloat16* Cb = C + batch * sC + ks * 512;
#pragma unroll
    for (int i = 0; i < 2; ++i) {
        int mb = m0 + wm + i * 16 + hi * 4;
#pragma unroll
        for (int j = 0; j < 2; ++j) {
            int nl = n0 + wn + j * 16 + ln;
            bh4 mv;
            mv.x = __float2bfloat16(acc[i][j][0]);
            mv.y = __float2bfloat16(acc[i][j][1]);
            mv.z = __float2bfloat16(acc[i][j][2]);
            mv.w = __float2bfloat16(acc[i][j][3]);
            Cb[(long long)(mb + 0) * ldc + nl] = mv.x;
            Cb[(long long)(mb + 1) * ldc + nl] = mv.y;
            Cb[(long long)(mb + 2) * ldc + nl] = mv.z;
            Cb[(long long)(mb + 3) * ldc + nl] = mv.w;
            if (mt != nt)
                *(bh4*)&Cb[(long long)nl * ldc + mb] = mv;   // mirrored tile
        }
    }
}

// Small MFMA GEMM, 64x64 tile, BK=64, operands K-contiguous.
// MODE 5: plain bf16 store.
// MODE 6: bf16 store of (acc + u[m]·sq[b][n] + ps[b][m]·r[n])/N + u[m]·r[n].
// Counted-vmcnt double-buffered K-loop (same scheme as mfma_g).
template<int MODE>
__global__ __launch_bounds__(256)
void mfma_sm(const __hip_bfloat16* __restrict__ A, long long sA, int lda,
             const __hip_bfloat16* __restrict__ B, long long sB, int ldb,
             __hip_bfloat16* __restrict__ C, long long sC, int ldc,
             const float* __restrict__ pu, const float* __restrict__ pr,
             const float* __restrict__ pps, const float* __restrict__ psq,
             int kLen)
{
    constexpr int BKT = 64;
    constexpr int CPR = BKT / 8;
    constexpr int NC = 64 * CPR / 256;
    constexpr int LSZ = 64 * BKT;
    __shared__ __hip_bfloat16 As[2 * LSZ];
    __shared__ __hip_bfloat16 Bs[2 * LSZ];
    const int tid = threadIdx.x;
    const int lane = tid & 63;
    const int w = tid >> 6;
    const int wm = (w >> 1) << 5;
    const int wn = (w & 1) << 5;
    const int ln = lane & 15;
    const int hi = lane >> 4;
    const int batch = blockIdx.x;
    const int m0 = blockIdx.z << 6;
    const int n0 = blockIdx.y << 6;

    const __hip_bfloat16* gA[NC];
    const __hip_bfloat16* gB[NC];
#pragma unroll
    for (int q0 = 0; q0 < NC; ++q0) {
        int q = tid + 256 * q0;
        int row = q / CPR;
        int c = (q % CPR) ^ SWZ64(row);
        gA[q0] = A + batch * sA + (long long)(m0 + row) * lda + c * 8;
        gB[q0] = B + batch * sB + (long long)(n0 + row) * ldb + c * 8;
    }
    floatx4 acc[2][2] = {};
    const int nK = kLen / BKT;

#pragma unroll
    for (int q0 = 0; q0 < NC; ++q0) {
        load_lds16(gA[q0], As + (tid + 256 * q0) * 8);
        load_lds16(gB[q0], Bs + (tid + 256 * q0) * 8);
        gA[q0] += BKT; gB[q0] += BKT;
    }

    int cur = 0;
    for (int kt = 0; kt < nK; ++kt) {
        if (kt + 1 < nK) {
            const int off = (cur ^ 1) * LSZ;
#pragma unroll
            for (int q0 = 0; q0 < NC; ++q0) {
                load_lds16(gA[q0], As + off + (tid + 256 * q0) * 8);
                load_lds16(gB[q0], Bs + off + (tid + 256 * q0) * 8);
                gA[q0] += BKT; gB[q0] += BKT;
            }
            asm volatile("s_waitcnt vmcnt(4)" ::: "memory");
        } else {
            asm volatile("s_waitcnt vmcnt(0)" ::: "memory");
        }
        __builtin_amdgcn_s_barrier();
        const __hip_bfloat16* Ac = As + cur * LSZ;
        const __hip_bfloat16* Bc = Bs + cur * LSZ;
#pragma unroll
        for (int kk = 0; kk < BKT / 32; ++kk) {
            const int cidx = kk * 4 + hi;
            bf16x8 af[2], bfr[2];
#pragma unroll
            for (int i = 0; i < 2; ++i) {
                int row = wm + i * 16 + ln;
                af[i] = *(const bf16x8*)(Ac + row * BKT + ((cidx ^ SWZ64(row)) << 3));
            }
#pragma unroll
            for (int j = 0; j < 2; ++j) {
                int row = wn + j * 16 + ln;
                bfr[j] = *(const bf16x8*)(Bc + row * BKT + ((cidx ^ SWZ64(row)) << 3));
            }
#pragma unroll
            for (int i = 0; i < 2; ++i)
#pragma unroll
                for (int j = 0; j < 2; ++j)
                    acc[i][j] = __builtin_amdgcn_mfma_f32_16x16x32_bf16(af[i], bfr[j], acc[i][j], 0, 0, 0);
        }
        if (kt + 1 < nK) {
            __builtin_amdgcn_s_barrier();
            cur ^= 1;
        }
    }

    __hip_bfloat16* Cb = C + batch * sC;
#pragma unroll
    for (int i = 0; i < 2; ++i) {
        int mb = m0 + wm + i * 16 + hi * 4;
#pragma unroll
        for (int r = 0; r < 4; ++r) {
#pragma unroll
            for (int j = 0; j < 2; ++j) {
                int nl = n0 + wn + j * 16 + ln;
                float v = acc[i][j][r];
                if (MODE == 6) {
                    float uu = pu[mb + r], rr = pr[nl];
                    v = (v + uu * psq[batch * 512 + nl] + pps[batch * 512 + mb + r] * rr)
                        * (1.f / 3136.f) + uu * rr;
                }
                Cb[(long long)(mb + r) * ldc + nl] = __float2bfloat16(v);
            }
        }
    }
}

// Final MFMA GEMM: 64(M)x128(N) tile, 4 waves (64x32 each), BK=64.
// EXACT R0 config (47.5us measured best). Grid: x = batch (XCD affinity),
// y = n-tile (25), z = m-tile (8). Residual x prefetched into VGPRs before the
// K-loop (completes under the loop's vmcnt drains).
__global__ __launch_bounds__(256)
void mfma64(const __hip_bfloat16* __restrict__ A, long long sA, int lda,
            const __hip_bfloat16* __restrict__ B, long long sB, int ldb,
            float* __restrict__ C, long long sC, int ldc,
            const float* __restrict__ bias, int sBias,
            const float* __restrict__ xres, long long sX,
            int kLen, int Nreal)
{
    constexpr int BKT = 64;
    constexpr int CPR = BKT / 8;
    constexpr int NA = 64 * CPR / 256;
    constexpr int NB = 128 * CPR / 256;
    __shared__ __hip_bfloat16 As[64 * BKT];
    __shared__ __hip_bfloat16 Bs[128 * BKT];
    const int tid = threadIdx.x;
    const int lane = tid & 63;
    const int w = tid >> 6;
    const int ln = lane & 15;
    const int hi = lane >> 4;
    const int batch = blockIdx.x;
    const int m0 = blockIdx.z << 6;
    const int n0 = blockIdx.y << 7;

    const __hip_bfloat16* gA[NA];
    const __hip_bfloat16* gB[NB];
#pragma unroll
    for (int q0 = 0; q0 < NA; ++q0) {
        int q = tid + 256 * q0;
        int row = q / CPR;
        int c = (q % CPR) ^ SWZ64(row);
        gA[q0] = A + batch * sA + (long long)(m0 + row) * lda + c * 8;
    }
#pragma unroll
    for (int q0 = 0; q0 < NB; ++q0) {
        int q = tid + 256 * q0;
        int row = q / CPR;
        int c = (q % CPR) ^ SWZ64(row);
        gB[q0] = B + batch * sB + (long long)(n0 + row) * ldb + c * 8;
    }

    // residual prefetch (clamped for the n-pad tail)
    const float* xb = xres + batch * sX;
    float xr[4][4][2];
#pragma unroll
    for (int i = 0; i < 4; ++i)
#pragma unroll
        for (int r = 0; r < 4; ++r)
#pragma unroll
            for (int j = 0; j < 2; ++j) {
                int mb = m0 + i * 16 + hi * 4 + r;
                int nl = n0 + w * 32 + j * 16 + ln;
                int nlc = nl < Nreal ? nl : Nreal - 1;
                xr[i][r][j] = xb[(long long)mb * ldc + nlc];
            }

    floatx4 acc[4][2] = {};
    const int nK = kLen / BKT;
    for (int kt = 0; kt < nK; ++kt) {
#pragma unroll
        for (int q0 = 0; q0 < NA; ++q0) {
            load_lds16(gA[q0], As + (tid + 256 * q0) * 8);
            gA[q0] += BKT;
        }
#pragma unroll
        for (int q0 = 0; q0 < NB; ++q0) {
            load_lds16(gB[q0], Bs + (tid + 256 * q0) * 8);
            gB[q0] += BKT;
        }
        __syncthreads();
#pragma unroll
        for (int kk = 0; kk < BKT / 32; ++kk) {
            const int cidx = kk * 4 + hi;
            bf16x8 af[4], bfr[2];
#pragma unroll
            for (int i = 0; i < 4; ++i) {
                int row = i * 16 + ln;
                af[i] = *(const bf16x8*)(As + row * BKT + ((cidx ^ SWZ64(row)) << 3));
            }
#pragma unroll
            for (int j = 0; j < 2; ++j) {
                int row = w * 32 + j * 16 + ln;
                bfr[j] = *(const bf16x8*)(Bs + row * BKT + ((cidx ^ SWZ64(row)) << 3));
            }
#pragma unroll
            for (int i = 0; i < 4; ++i)
#pragma unroll
                for (int j = 0; j < 2; ++j)
                    acc[i][j] = __builtin_amdgcn_mfma_f32_16x16x32_bf16(af[i], bfr[j], acc[i][j], 0, 0, 0);
        }
        __syncthreads();
    }

    float* Cb = C + batch * sC;
#pragma unroll
    for (int i = 0; i < 4; ++i) {
        int mb = m0 + i * 16 + hi * 4;
#pragma unroll
        for (int r = 0; r < 4; ++r) {
            float bb = bias[batch * sBias + mb + r];
#pragma unroll
            for (int j = 0; j < 2; ++j) {
                int nl = n0 + w * 32 + j * 16 + ln;
                if (nl < Nreal) {
                    Cb[(long long)(mb + r) * ldc + nl] = acc[i][j][r] + bb + xr[i][r][j];
                }
            }
        }
    }
}

extern "C" void kernel_launch(void* const* d_in, const int* in_sizes, int n_in,
                              void* d_out, int out_size, void* d_ws, size_t ws_size,
                              hipStream_t stream)
{
    const float* x  = (const float*)d_in[0];
    const float* wq = (const float*)d_in[1];
    const float* bq = (const float*)d_in[2];
    const float* wk = (const float*)d_in[3];
    const float* bk = (const float*)d_in[4];
    const float* wv = (const float*)d_in[5];
    const float* bv = (const float*)d_in[6];
    const float* wo = (const float*)d_in[7];
    const float* bo = (const float*)d_in[8];
    float* out = (float*)d_out;

    const int N = 3136;
    const long long xs = 512LL * N;               // 1,605,632
    const long long xs2 = 512LL * 3200;           // xnp per-batch stride

    // d_out scratch (51.4 MB), all dead before the final GEMM writes out:
    char* ob = (char*)d_out;
    __hip_bfloat16* xnp = (__hip_bfloat16*)ob;                 // @0: 26,214,400 (dead after G)
    __hip_bfloat16* Gp2 = (__hip_bfloat16*)(ob + 26214400);    // 8x512x1024 bf16 = 8,388,608
    __hip_bfloat16* Tb  = (__hip_bfloat16*)(ob + 34603008);    // 8x512x512 bf16 = 4,194,304

    // ws (~32.05 MB). Final GEMM reads only ws + x.
    char* wsb = (char*)d_ws;
    __hip_bfloat16* xT  = (__hip_bfloat16*)wsb;                // 26,214,400
    __hip_bfloat16* A2b = (__hip_bfloat16*)(wsb + 26214400);   //  4,194,304
    __hip_bfloat16* Pdb = (__hip_bfloat16*)(wsb + 30408704);   //  1,048,576
    __hip_bfloat16* Qtb = (__hip_bfloat16*)(wsb + 31457280);   //    524,288
    float* sv  = (float*)(wsb + 31981568);                     //     16,384
    float* u_  = (float*)(wsb + 31997952);                     //      2,048
    float* r_  = (float*)(wsb + 32000000);                     //      2,048
    float* w_  = (float*)(wsb + 32002048);                     //      2,048
    float* kap = (float*)(wsb + 32004096);                     //         16
    float* ps  = (float*)(wsb + 32004112);                     //     16,384
    float* sq  = (float*)(wsb + 32020496);                     //     16,384
    float* a2v = (float*)(wsb + 32036880);                     //     16,384

    // 1) fused data-independent precompute (P/Qt/u/r/w/kap + zero s)
    prep_all<<<dim3(8, 8, 3), 256, 0, stream>>>(wo, wv, wq, wk, bq, bk, bv,
                                                Pdb, Qtb, u_, r_, w_, kap, sv);

    // 2) xT + xnp + s (16B stores)
    transpose_conv<<<dim3(50, 8, 8), 256, 0, stream>>>(x, xT, xnp, sv);

    // 3) Gp2 = partials of X·X^T  (split-K=2, K=1600, BK=64), symmetric:
    //    36 upper-tri tile pairs x 16 (batch,ks) = 576 blocks, mirror on store
    mfma_g<<<dim3(16, 36), 256, 0, stream>>>(
        xnp, xs2, 3200, Gp2, 524288, 1024, 1600);

    // 4) T = Pd·Gp2  (K=1024 folds the split-K reduce)
    mfma_sm<5><<<dim3(8, 8, 8), 256, 0, stream>>>(
        Pdb, 0, 1024, Gp2, 524288, 1024, Tb, 262144, 512,
        nullptr, nullptr, nullptr, nullptr, 1024);

    // 5) ps = P·s, sq = Qt·s, a2 = [T·w + u(s·w) + ps·κ]/N + uκ + bo
    vec2_kernel<<<1024, 256, 0, stream>>>(Tb, Pdb, Qtb, sv, u_, w_, kap, bo, ps, sq, a2v);

    // 6) A2 = [T·Q + u·sq^T + ps·r^T]/N + u·r^T  -> bf16
    mfma_sm<6><<<dim3(8, 8, 8), 256, 0, stream>>>(
        Tb, 262144, 512, Qtb, 0, 512, A2b, 262144, 512,
        u_, r_, ps, sq, 512);

    // 7) out = A2·X + a2 + x   (M=512, N=3136, K=512)
    mfma64<<<dim3(8, 25, 8), 256, 0, stream>>>(
        A2b, 262144, 512, xT, 3200LL * 512, 512,
        out, xs, N, a2v, 512, x, xs, 512, N);
}

// Round 5
// 212.822 us; speedup vs baseline: 1.3375x; 1.0743x over previous
//
#include <hip/hip_runtime.h>
#include <hip/hip_bf16.h>

// DotProductNonLocalBlock: B=8, C=512, N=3136 (pad 3200), E=256.
// No softmax => fully associative. Factored with DATA-INDEPENDENT
// P = wo·wv, Qt = wq^T·wk, u = wo·bv, r = bk^T·wq, w = Wk^T·bq, κ = bk·bq:
//   G  = X·X^T   [bf16 MFMA, split-K=2 col-interleaved partials, SYMMETRIC]
//   T  = Pd·Gp2 (K=1024 folds the reduce)
//   A2 = [T·Q + u·(Qt s)^T + (P s)·r^T]/N + u·r^T  (+ I — residual folded in, R5)
//   a2 = [T·w + u·(s·w) + (P s)·κ]/N + u·κ + bo
//   Out = (A2+I)·X + a2        [residual x = I·X absorbed into A2's diagonal;
//                               residual now rides the bf16 xT path]
// Batch in blockIdx.x on all MFMA grids (XCD affinity; per-batch panels fit 4MB L2).
// LEDGER final GEMM: 64x128 single-buf = 47.5us (BEST) | dbuf-drain = 52.2 |
//   128x128 single-buf = 59.3 | zero-LDS = 107. Counted-vmcnt on g/sm: NEUTRAL
//   (R4 total == R0 total; T4 is gated on 8-phase schedules, null on 2-phase).
// Round 11: (a) identity-fold residual -> mfma64 loses the 51.4MB fp32 x read
//   + 32-VGPR prefetch; (b) prep_all+transpose_conv merged into one launch
//   (independent inputs; prep's 131 blocks ride the transpose grid's tail).

typedef __attribute__((ext_vector_type(8))) __bf16 bf16x8;
typedef __attribute__((ext_vector_type(4))) float floatx4;

struct __align__(8) bh4 { __hip_bfloat16 x, y, z, w; };
struct __align__(16) bh8 { __hip_bfloat16 h[8]; };

__device__ __forceinline__ void load_lds16(const void* g, void* l) {
    __builtin_amdgcn_global_load_lds((const __attribute__((address_space(1))) void*)g,
                                     (__attribute__((address_space(3))) void*)l, 16, 0, 0);
}

// ---- fused: data-independent precompute + x transpose/convert ----
// z in [0,8): transpose_conv for batch z.
// z == 8: blk = y*50+x:
//   blk in [0,64)   -> Pd tile (P = wo·wv, duplicated [P|P])
//   blk in [64,128) -> Qt tile (wq^T·wk)
//   blk 128,129     -> u/r/w vectors (256 channels each)
//   blk 130         -> zero s accumulator
__global__ __launch_bounds__(256)
void prep_trans(const float* __restrict__ x, __hip_bfloat16* __restrict__ xT,
                __hip_bfloat16* __restrict__ xnp, float* __restrict__ s,
                const float* __restrict__ wo, const float* __restrict__ wv,
                const float* __restrict__ wq, const float* __restrict__ wk,
                const float* __restrict__ bq, const float* __restrict__ bk,
                const float* __restrict__ bv,
                __hip_bfloat16* __restrict__ Pdb, __hip_bfloat16* __restrict__ Qtb,
                float* __restrict__ u, float* __restrict__ r, float* __restrict__ w,
                float* __restrict__ kap)
{
    __shared__ __align__(16) float smem[64 * 65];   // 16.6KB arena, both paths
    const int tid = threadIdx.x;

    if (blockIdx.z == 8) {
        // ---------- prep path ----------
        const int blk = blockIdx.y * 50 + blockIdx.x;
        if (blk >= 131) return;
        if (blk >= 128) {
            int blk2 = blk - 128;
            if (blk2 < 2) {
                int c = blk2 * 256 + tid;
                float su = 0.f, sr = 0.f, sw = 0.f;
                for (int e = 0; e < 256; ++e) {
                    su = fmaf(wo[(long long)c * 256 + e], bv[e], su);
                    sr = fmaf(bk[e], wq[(long long)e * 512 + c], sr);
                    sw = fmaf(wk[(long long)e * 512 + c], bq[e], sw);
                }
                u[c] = su; r[c] = sr; w[c] = sw;
                if (c == 0) {
                    float k2 = 0.f;
                    for (int e = 0; e < 256; ++e) k2 = fmaf(bk[e], bq[e], k2);
                    *kap = k2;
                }
            } else {
                float4* p = (float4*)s;
                for (int i = tid; i < 1024; i += 256) p[i] = make_float4(0.f, 0.f, 0.f, 0.f);
            }
            return;
        }
        const bool doQ = (blk >= 64);
        const int tt = blk & 63;
        const int m0 = (tt >> 3) * 64, n0 = (tt & 7) * 64;
        float (*As)[68] = (float(*)[68])smem;
        float (*Bs)[68] = (float(*)[68])(smem + 16 * 68);
        const int tx = tid & 15, ty = tid >> 4;
        const int lk = tid >> 4, lc = (tid & 15) * 4;
        const int lr = tid >> 2, lk4 = (tid & 3) * 4;
        float acc[4][4] = {};
        for (int k0 = 0; k0 < 256; k0 += 16) {
            float4 av, bv4;
            if (doQ) {
                av = *(const float4*)&wq[(long long)(k0 + lk) * 512 + m0 + lc];
                bv4 = *(const float4*)&wk[(long long)(k0 + lk) * 512 + n0 + lc];
            } else {
                av = *(const float4*)&wo[(long long)(m0 + lr) * 256 + k0 + lk4];
                bv4 = *(const float4*)&wv[(long long)(k0 + lk) * 512 + n0 + lc];
            }
            __syncthreads();
            if (doQ) {
                *(float4*)&As[lk][lc] = av;
            } else {
                As[lk4 + 0][lr] = av.x; As[lk4 + 1][lr] = av.y;
                As[lk4 + 2][lr] = av.z; As[lk4 + 3][lr] = av.w;
            }
            *(float4*)&Bs[lk][lc] = bv4;
            __syncthreads();
#pragma unroll
            for (int kk = 0; kk < 16; ++kk) {
                float a[4], b[4];
#pragma unroll
                for (int i = 0; i < 4; ++i) { a[i] = As[kk][ty * 4 + i]; b[i] = Bs[kk][tx * 4 + i]; }
#pragma unroll
                for (int i = 0; i < 4; ++i)
#pragma unroll
                    for (int j = 0; j < 4; ++j) acc[i][j] = fmaf(a[i], b[j], acc[i][j]);
            }
        }
        const int mo = m0 + ty * 4, no = n0 + tx * 4;
        if (doQ) {
#pragma unroll
            for (int i = 0; i < 4; ++i)
#pragma unroll
                for (int j = 0; j < 4; ++j)
                    Qtb[(long long)(mo + i) * 512 + no + j] = __float2bfloat16(acc[i][j]);
        } else {
#pragma unroll
            for (int i = 0; i < 4; ++i)
#pragma unroll
                for (int j = 0; j < 4; ++j) {
                    __hip_bfloat16 v = __float2bfloat16(acc[i][j]);
                    Pdb[(long long)(mo + i) * 1024 + no + j] = v;
                    Pdb[(long long)(mo + i) * 1024 + no + j + 512] = v;
                }
        }
        return;
    }

    // ---------- transpose path ----------
    // x [b][512][3136] fp32 -> xT [b][3200][512] bf16 (pad rows zero)
    //                        + xnp [b][512][3200] bf16 (pad cols zero)
    //                        + s[b][c] += rowsums (atomic)
    float (*t)[65] = (float(*)[65])smem;
    const int b = blockIdx.z;
    const int n0 = blockIdx.x * 64, c0 = blockIdx.y * 64;
    const int nch = tid & 7;      // 8-wide chunk index
    const int cr  = tid >> 3;     // 0..31 row-within-pass
    __hip_bfloat16* xTo = xT + (long long)b * 3200 * 512;
    __hip_bfloat16* xno = xnp + (long long)b * 512 * 3200;

    if (n0 >= 3136) {             // pad tile
        bh8 z8;
#pragma unroll
        for (int k = 0; k < 8; ++k) z8.h[k] = __float2bfloat16(0.f);
#pragma unroll
        for (int pass = 0; pass < 2; ++pass) {
            int rr = cr + 32 * pass;
            *(bh8*)&xno[(long long)(c0 + rr) * 3200 + n0 + nch * 8] = z8;
            *(bh8*)&xTo[(long long)(n0 + rr) * 512 + c0 + nch * 8] = z8;
        }
        return;
    }
    const float* xb = x + (long long)b * 512 * 3136;
#pragma unroll
    for (int pass = 0; pass < 2; ++pass) {
        const int cl = cr + 32 * pass;
        const int c = c0 + cl;
        const float* xr = xb + (long long)c * 3136 + n0 + nch * 8;
        float4 v0 = *(const float4*)xr;
        float4 v1 = *(const float4*)(xr + 4);
        bh8 o;
        o.h[0] = __float2bfloat16(v0.x); o.h[1] = __float2bfloat16(v0.y);
        o.h[2] = __float2bfloat16(v0.z); o.h[3] = __float2bfloat16(v0.w);
        o.h[4] = __float2bfloat16(v1.x); o.h[5] = __float2bfloat16(v1.y);
        o.h[6] = __float2bfloat16(v1.z); o.h[7] = __float2bfloat16(v1.w);
        *(bh8*)&xno[(long long)c * 3200 + n0 + nch * 8] = o;
        const int nl = nch * 8;
        t[nl + 0][cl] = v0.x; t[nl + 1][cl] = v0.y;
        t[nl + 2][cl] = v0.z; t[nl + 3][cl] = v0.w;
        t[nl + 4][cl] = v1.x; t[nl + 5][cl] = v1.y;
        t[nl + 6][cl] = v1.z; t[nl + 7][cl] = v1.w;
        float rs = v0.x + v0.y + v0.z + v0.w + v1.x + v1.y + v1.z + v1.w;
        rs += __shfl_xor(rs, 1, 8);
        rs += __shfl_xor(rs, 2, 8);
        rs += __shfl_xor(rs, 4, 8);
        if (nch == 0) atomicAdd(&s[b * 512 + c], rs);
    }
    __syncthreads();
#pragma unroll
    for (int pass = 0; pass < 2; ++pass) {
        const int nl = cr + 32 * pass;
        const int cc = nch * 8;
        bh8 o;
#pragma unroll
        for (int k = 0; k < 8; ++k) o.h[k] = __float2bfloat16(t[nl][cc + k]);
        *(bh8*)&xTo[(long long)(n0 + nl) * 512 + c0 + cc] = o;
    }
}

// Wave-per-output: ps = P·s, sq = Qt·s, a2 = [T·w + u(s·w) + ps·κ]/N + uκ + bo.
__global__ __launch_bounds__(256)
void vec2_kernel(const __hip_bfloat16* __restrict__ T, const __hip_bfloat16* __restrict__ Pdb,
                 const __hip_bfloat16* __restrict__ Qtb, const float* __restrict__ s,
                 const float* __restrict__ u, const float* __restrict__ w,
                 const float* __restrict__ kap, const float* __restrict__ bo,
                 float* __restrict__ ps, float* __restrict__ sq, float* __restrict__ a2)
{
    const int idx = blockIdx.x * 4 + (threadIdx.x >> 6);   // b*512+c
    const int lane = threadIdx.x & 63;
    const int b = idx >> 9, c = idx & 511;
    const int j0 = lane * 8;
    const float* sb = s + b * 512;
    float4 s0 = *(const float4*)&sb[j0], s1 = *(const float4*)&sb[j0 + 4];
    float4 w0 = *(const float4*)&w[j0],  w1 = *(const float4*)&w[j0 + 4];
    bf16x8 pv = *(const bf16x8*)&Pdb[(long long)c * 1024 + j0];
    bf16x8 qv = *(const bf16x8*)&Qtb[(long long)c * 512 + j0];
    bf16x8 tv = *(const bf16x8*)&T[(long long)b * 262144 + (long long)c * 512 + j0];
    float sj[8] = {s0.x, s0.y, s0.z, s0.w, s1.x, s1.y, s1.z, s1.w};
    float wj[8] = {w0.x, w0.y, w0.z, w0.w, w1.x, w1.y, w1.z, w1.w};
    float aps = 0.f, asq = 0.f, atw = 0.f, asw = 0.f;
#pragma unroll
    for (int t = 0; t < 8; ++t) {
        aps = fmaf((float)pv[t], sj[t], aps);
        asq = fmaf((float)qv[t], sj[t], asq);
        atw = fmaf((float)tv[t], wj[t], atw);
        asw = fmaf(sj[t], wj[t], asw);
    }
#pragma unroll
    for (int m = 1; m < 64; m <<= 1) {
        aps += __shfl_xor(aps, m);
        asq += __shfl_xor(asq, m);
        atw += __shfl_xor(atw, m);
        asw += __shfl_xor(asw, m);
    }
    if (lane == 0) {
        ps[idx] = aps; sq[idx] = asq;
        float kp = *kap;
        a2[idx] = (atw + u[c] * asw + aps * kp) * (1.f / 3136.f) + u[c] * kp + bo[c];
    }
}

#define SWZ64(row) ((row) & 7)

// G GEMM with symmetric mirroring. 64x64 tile, BK=64, operands = xnp (both).
// Grid: x = batch + 8*ks (XCD affinity), y = triangular pair index (36).
// Counted-vmcnt double-buffered K-loop (neutral vs dbuf-drain, kept).
__global__ __launch_bounds__(256)
void mfma_g(const __hip_bfloat16* __restrict__ A, long long sA, int lda,
            __hip_bfloat16* __restrict__ C, long long sC, int ldc,
            int kLen)
{
    constexpr int BKT = 64;
    constexpr int CPR = BKT / 8;
    constexpr int NC = 64 * CPR / 256;
    constexpr int LSZ = 64 * BKT;
    __shared__ __hip_bfloat16 As[2 * LSZ];
    __shared__ __hip_bfloat16 Bs[2 * LSZ];
    const int tid = threadIdx.x;
    const int lane = tid & 63;
    const int w = tid >> 6;
    const int wm = (w >> 1) << 5;
    const int wn = (w & 1) << 5;
    const int ln = lane & 15;
    const int hi = lane >> 4;
    const int bx = blockIdx.x;
    const int batch = bx & 7, ks = bx >> 3;
    int p = blockIdx.y, mt = 0;
    while (p >= 8 - mt) { p -= 8 - mt; ++mt; }
    const int nt = mt + p;
    const int m0 = mt << 6, n0 = nt << 6;
    const long long k0 = (long long)ks * kLen;

    const __hip_bfloat16* gA[NC];
    const __hip_bfloat16* gB[NC];
#pragma unroll
    for (int q0 = 0; q0 < NC; ++q0) {
        int q = tid + 256 * q0;
        int row = q / CPR;
        int c = (q % CPR) ^ SWZ64(row);
        gA[q0] = A + batch * sA + (long long)(m0 + row) * lda + k0 + c * 8;
        gB[q0] = A + batch * sA + (long long)(n0 + row) * lda + k0 + c * 8;
    }
    floatx4 acc[2][2] = {};
    const int nK = kLen / BKT;

    // prologue: stage tile 0 into buffer 0 (4 loads/thread in flight)
#pragma unroll
    for (int q0 = 0; q0 < NC; ++q0) {
        load_lds16(gA[q0], As + (tid + 256 * q0) * 8);
        load_lds16(gB[q0], Bs + (tid + 256 * q0) * 8);
        gA[q0] += BKT; gB[q0] += BKT;
    }

    int cur = 0;
    for (int kt = 0; kt < nK; ++kt) {
        if (kt + 1 < nK) {
            const int off = (cur ^ 1) * LSZ;
#pragma unroll
            for (int q0 = 0; q0 < NC; ++q0) {
                load_lds16(gA[q0], As + off + (tid + 256 * q0) * 8);
                load_lds16(gB[q0], Bs + off + (tid + 256 * q0) * 8);
                gA[q0] += BKT; gB[q0] += BKT;
            }
            asm volatile("s_waitcnt vmcnt(4)" ::: "memory");   // cur tile landed; next in flight
        } else {
            asm volatile("s_waitcnt vmcnt(0)" ::: "memory");   // final tile landed
        }
        __builtin_amdgcn_s_barrier();
        const __hip_bfloat16* Ac = As + cur * LSZ;
        const __hip_bfloat16* Bc = Bs + cur * LSZ;
#pragma unroll
        for (int kk = 0; kk < BKT / 32; ++kk) {
            const int cidx = kk * 4 + hi;
            bf16x8 af[2], bfr[2];
#pragma unroll
            for (int i = 0; i < 2; ++i) {
                int row = wm + i * 16 + ln;
                af[i] = *(const bf16x8*)(Ac + row * BKT + ((cidx ^ SWZ64(row)) << 3));
            }
#pragma unroll
            for (int j = 0; j < 2; ++j) {
                int row = wn + j * 16 + ln;
                bfr[j] = *(const bf16x8*)(Bc + row * BKT + ((cidx ^ SWZ64(row)) << 3));
            }
#pragma unroll
            for (int i = 0; i < 2; ++i)
#pragma unroll
                for (int j = 0; j < 2; ++j)
                    acc[i][j] = __builtin_amdgcn_mfma_f32_16x16x32_bf16(af[i], bfr[j], acc[i][j], 0, 0, 0);
        }
        if (kt + 1 < nK) {
            __builtin_amdgcn_s_barrier();   // buf[cur] fully read -> safe to restage next iter
            cur ^= 1;
        }
    }

    // C/D layout: col = lane&15, row = (lane>>4)*4 + r  [m89-verified]
    __hip_bfloat16* Cb = C + batch * sC + ks * 512;
#pragma unroll
    for (int i = 0; i < 2; ++i) {
        int mb = m0 + wm + i * 16 + hi * 4;
#pragma unroll
        for (int j = 0; j < 2; ++j) {
            int nl = n0 + wn + j * 16 + ln;
            bh4 mv;
            mv.x = __float2bfloat16(acc[i][j][0]);
            mv.y = __float2bfloat16(acc[i][j][1]);
            mv.z = __float2bfloat16(acc[i][j][2]);
            mv.w = __float2bfloat16(acc[i][j][3]);
            Cb[(long long)(mb + 0) * ldc + nl] = mv.x;
            Cb[(long long)(mb + 1) * ldc + nl] = mv.y;
            Cb[(long long)(mb + 2) * ldc + nl] = mv.z;
            Cb[(long long)(mb + 3) * ldc + nl] = mv.w;
            if (mt != nt)
                *(bh4*)&Cb[(long long)nl * ldc + mb] = mv;   // mirrored tile
        }
    }
}

// Small MFMA GEMM, 64x64 tile, BK=64, operands K-contiguous.
// MODE 5: plain bf16 store.
// MODE 6: bf16 store of (acc + u[m]·sq[b][n] + ps[b][m]·r[n])/N + u[m]·r[n]
//         + IDENTITY on the diagonal (residual x folded into A2, R5).
// Counted-vmcnt double-buffered K-loop.
template<int MODE>
__global__ __launch_bounds__(256)
void mfma_sm(const __hip_bfloat16* __restrict__ A, long long sA, int lda,
             const __hip_bfloat16* __restrict__ B, long long sB, int ldb,
             __hip_bfloat16* __restrict__ C, long long sC, int ldc,
             const float* __restrict__ pu, const float* __restrict__ pr,
             const float* __restrict__ pps, const float* __restrict__ psq,
             int kLen)
{
    constexpr int BKT = 64;
    constexpr int CPR = BKT / 8;
    constexpr int NC = 64 * CPR / 256;
    constexpr int LSZ = 64 * BKT;
    __shared__ __hip_bfloat16 As[2 * LSZ];
    __shared__ __hip_bfloat16 Bs[2 * LSZ];
    const int tid = threadIdx.x;
    const int lane = tid & 63;
    const int w = tid >> 6;
    const int wm = (w >> 1) << 5;
    const int wn = (w & 1) << 5;
    const int ln = lane & 15;
    const int hi = lane >> 4;
    const int batch = blockIdx.x;
    const int m0 = blockIdx.z << 6;
    const int n0 = blockIdx.y << 6;

    const __hip_bfloat16* gA[NC];
    const __hip_bfloat16* gB[NC];
#pragma unroll
    for (int q0 = 0; q0 < NC; ++q0) {
        int q = tid + 256 * q0;
        int row = q / CPR;
        int c = (q % CPR) ^ SWZ64(row);
        gA[q0] = A + batch * sA + (long long)(m0 + row) * lda + c * 8;
        gB[q0] = B + batch * sB + (long long)(n0 + row) * ldb + c * 8;
    }
    floatx4 acc[2][2] = {};
    const int nK = kLen / BKT;

#pragma unroll
    for (int q0 = 0; q0 < NC; ++q0) {
        load_lds16(gA[q0], As + (tid + 256 * q0) * 8);
        load_lds16(gB[q0], Bs + (tid + 256 * q0) * 8);
        gA[q0] += BKT; gB[q0] += BKT;
    }

    int cur = 0;
    for (int kt = 0; kt < nK; ++kt) {
        if (kt + 1 < nK) {
            const int off = (cur ^ 1) * LSZ;
#pragma unroll
            for (int q0 = 0; q0 < NC; ++q0) {
                load_lds16(gA[q0], As + off + (tid + 256 * q0) * 8);
                load_lds16(gB[q0], Bs + off + (tid + 256 * q0) * 8);
                gA[q0] += BKT; gB[q0] += BKT;
            }
            asm volatile("s_waitcnt vmcnt(4)" ::: "memory");
        } else {
            asm volatile("s_waitcnt vmcnt(0)" ::: "memory");
        }
        __builtin_amdgcn_s_barrier();
        const __hip_bfloat16* Ac = As + cur * LSZ;
        const __hip_bfloat16* Bc = Bs + cur * LSZ;
#pragma unroll
        for (int kk = 0; kk < BKT / 32; ++kk) {
            const int cidx = kk * 4 + hi;
            bf16x8 af[2], bfr[2];
#pragma unroll
            for (int i = 0; i < 2; ++i) {
                int row = wm + i * 16 + ln;
                af[i] = *(const bf16x8*)(Ac + row * BKT + ((cidx ^ SWZ64(row)) << 3));
            }
#pragma unroll
            for (int j = 0; j < 2; ++j) {
                int row = wn + j * 16 + ln;
                bfr[j] = *(const bf16x8*)(Bc + row * BKT + ((cidx ^ SWZ64(row)) << 3));
            }
#pragma unroll
            for (int i = 0; i < 2; ++i)
#pragma unroll
                for (int j = 0; j < 2; ++j)
                    acc[i][j] = __builtin_amdgcn_mfma_f32_16x16x32_bf16(af[i], bfr[j], acc[i][j], 0, 0, 0);
        }
        if (kt + 1 < nK) {
            __builtin_amdgcn_s_barrier();
            cur ^= 1;
        }
    }

    __hip_bfloat16* Cb = C + batch * sC;
#pragma unroll
    for (int i = 0; i < 2; ++i) {
        int mb = m0 + wm + i * 16 + hi * 4;
#pragma unroll
        for (int r = 0; r < 4; ++r) {
#pragma unroll
            for (int j = 0; j < 2; ++j) {
                int nl = n0 + wn + j * 16 + ln;
                float v = acc[i][j][r];
                if (MODE == 6) {
                    float uu = pu[mb + r], rr = pr[nl];
                    v = (v + uu * psq[batch * 512 + nl] + pps[batch * 512 + mb + r] * rr)
                        * (1.f / 3136.f) + uu * rr;
                    if (mb + r == nl) v += 1.f;   // residual fold: A2 += I
                }
                Cb[(long long)(mb + r) * ldc + nl] = __float2bfloat16(v);
            }
        }
    }
}

// Final MFMA GEMM: 64(M)x128(N) tile, 4 waves (64x32 each), BK=64.
// R0 structure (measured best). Residual now folded into A2 -> no x read,
// no prefetch; epilogue = acc + bias only.
__global__ __launch_bounds__(256)
void mfma64(const __hip_bfloat16* __restrict__ A, long long sA, int lda,
            const __hip_bfloat16* __restrict__ B, long long sB, int ldb,
            float* __restrict__ C, long long sC, int ldc,
            const float* __restrict__ bias, int sBias,
            int kLen, int Nreal)
{
    constexpr int BKT = 64;
    constexpr int CPR = BKT / 8;
    constexpr int NA = 64 * CPR / 256;
    constexpr int NB = 128 * CPR / 256;
    __shared__ __hip_bfloat16 As[64 * BKT];
    __shared__ __hip_bfloat16 Bs[128 * BKT];
    const int tid = threadIdx.x;
    const int lane = tid & 63;
    const int w = tid >> 6;
    const int ln = lane & 15;
    const int hi = lane >> 4;
    const int batch = blockIdx.x;
    const int m0 = blockIdx.z << 6;
    const int n0 = blockIdx.y << 7;

    const __hip_bfloat16* gA[NA];
    const __hip_bfloat16* gB[NB];
#pragma unroll
    for (int q0 = 0; q0 < NA; ++q0) {
        int q = tid + 256 * q0;
        int row = q / CPR;
        int c = (q % CPR) ^ SWZ64(row);
        gA[q0] = A + batch * sA + (long long)(m0 + row) * lda + c * 8;
    }
#pragma unroll
    for (int q0 = 0; q0 < NB; ++q0) {
        int q = tid + 256 * q0;
        int row = q / CPR;
        int c = (q % CPR) ^ SWZ64(row);
        gB[q0] = B + batch * sB + (long long)(n0 + row) * ldb + c * 8;
    }

    floatx4 acc[4][2] = {};
    const int nK = kLen / BKT;
    for (int kt = 0; kt < nK; ++kt) {
#pragma unroll
        for (int q0 = 0; q0 < NA; ++q0) {
            load_lds16(gA[q0], As + (tid + 256 * q0) * 8);
            gA[q0] += BKT;
        }
#pragma unroll
        for (int q0 = 0; q0 < NB; ++q0) {
            load_lds16(gB[q0], Bs + (tid + 256 * q0) * 8);
            gB[q0] += BKT;
        }
        __syncthreads();
#pragma unroll
        for (int kk = 0; kk < BKT / 32; ++kk) {
            const int cidx = kk * 4 + hi;
            bf16x8 af[4], bfr[2];
#pragma unroll
            for (int i = 0; i < 4; ++i) {
                int row = i * 16 + ln;
                af[i] = *(const bf16x8*)(As + row * BKT + ((cidx ^ SWZ64(row)) << 3));
            }
#pragma unroll
            for (int j = 0; j < 2; ++j) {
                int row = w * 32 + j * 16 + ln;
                bfr[j] = *(const bf16x8*)(Bs + row * BKT + ((cidx ^ SWZ64(row)) << 3));
            }
#pragma unroll
            for (int i = 0; i < 4; ++i)
#pragma unroll
                for (int j = 0; j < 2; ++j)
                    acc[i][j] = __builtin_amdgcn_mfma_f32_16x16x32_bf16(af[i], bfr[j], acc[i][j], 0, 0, 0);
        }
        __syncthreads();
    }

    float* Cb = C + batch * sC;
#pragma unroll
    for (int i = 0; i < 4; ++i) {
        int mb = m0 + i * 16 + hi * 4;
#pragma unroll
        for (int r = 0; r < 4; ++r) {
            float bb = bias[batch * sBias + mb + r];
#pragma unroll
            for (int j = 0; j < 2; ++j) {
                int nl = n0 + w * 32 + j * 16 + ln;
                if (nl < Nreal) {
                    Cb[(long long)(mb + r) * ldc + nl] = acc[i][j][r] + bb;
                }
            }
        }
    }
}

extern "C" void kernel_launch(void* const* d_in, const int* in_sizes, int n_in,
                              void* d_out, int out_size, void* d_ws, size_t ws_size,
                              hipStream_t stream)
{
    const float* x  = (const float*)d_in[0];
    const float* wq = (const float*)d_in[1];
    const float* bq = (const float*)d_in[2];
    const float* wk = (const float*)d_in[3];
    const float* bk = (const float*)d_in[4];
    const float* wv = (const float*)d_in[5];
    const float* bv = (const float*)d_in[6];
    const float* wo = (const float*)d_in[7];
    const float* bo = (const float*)d_in[8];
    float* out = (float*)d_out;

    const int N = 3136;
    const long long xs = 512LL * N;               // 1,605,632
    const long long xs2 = 512LL * 3200;           // xnp per-batch stride

    // d_out scratch (51.4 MB), all dead before the final GEMM writes out:
    char* ob = (char*)d_out;
    __hip_bfloat16* xnp = (__hip_bfloat16*)ob;                 // @0: 26,214,400 (dead after G)
    __hip_bfloat16* Gp2 = (__hip_bfloat16*)(ob + 26214400);    // 8x512x1024 bf16 = 8,388,608
    __hip_bfloat16* Tb  = (__hip_bfloat16*)(ob + 34603008);    // 8x512x512 bf16 = 4,194,304

    // ws (~32.05 MB). Final GEMM reads only ws.
    char* wsb = (char*)d_ws;
    __hip_bfloat16* xT  = (__hip_bfloat16*)wsb;                // 26,214,400
    __hip_bfloat16* A2b = (__hip_bfloat16*)(wsb + 26214400);   //  4,194,304
    __hip_bfloat16* Pdb = (__hip_bfloat16*)(wsb + 30408704);   //  1,048,576
    __hip_bfloat16* Qtb = (__hip_bfloat16*)(wsb + 31457280);   //    524,288
    float* sv  = (float*)(wsb + 31981568);                     //     16,384
    float* u_  = (float*)(wsb + 31997952);                     //      2,048
    float* r_  = (float*)(wsb + 32000000);                     //      2,048
    float* w_  = (float*)(wsb + 32002048);                     //      2,048
    float* kap = (float*)(wsb + 32004096);                     //         16
    float* ps  = (float*)(wsb + 32004112);                     //     16,384
    float* sq  = (float*)(wsb + 32020496);                     //     16,384
    float* a2v = (float*)(wsb + 32036880);                     //     16,384

    // 1) fused: precompute (P/Qt/u/r/w/kap + zero s) + xT/xnp/s transpose
    prep_trans<<<dim3(50, 8, 9), 256, 0, stream>>>(
        x, xT, xnp, sv, wo, wv, wq, wk, bq, bk, bv,
        Pdb, Qtb, u_, r_, w_, kap);

    // 2) Gp2 = partials of X·X^T  (split-K=2, K=1600, BK=64), symmetric:
    //    36 upper-tri tile pairs x 16 (batch,ks) = 576 blocks, mirror on store
    mfma_g<<<dim3(16, 36), 256, 0, stream>>>(
        xnp, xs2, 3200, Gp2, 524288, 1024, 1600);

    // 3) T = Pd·Gp2  (K=1024 folds the split-K reduce)
    mfma_sm<5><<<dim3(8, 8, 8), 256, 0, stream>>>(
        Pdb, 0, 1024, Gp2, 524288, 1024, Tb, 262144, 512,
        nullptr, nullptr, nullptr, nullptr, 1024);

    // 4) ps = P·s, sq = Qt·s, a2 = [T·w + u(s·w) + ps·κ]/N + uκ + bo
    vec2_kernel<<<1024, 256, 0, stream>>>(Tb, Pdb, Qtb, sv, u_, w_, kap, bo, ps, sq, a2v);

    // 5) A2 = [T·Q + u·sq^T + ps·r^T]/N + u·r^T + I  -> bf16 (residual folded)
    mfma_sm<6><<<dim3(8, 8, 8), 256, 0, stream>>>(
        Tb, 262144, 512, Qtb, 0, 512, A2b, 262144, 512,
        u_, r_, ps, sq, 512);

    // 6) out = (A2+I)·X + a2   (M=512, N=3136, K=512)
    mfma64<<<dim3(8, 25, 8), 256, 0, stream>>>(
        A2b, 262144, 512, xT, 3200LL * 512, 512,
        out, xs, N, a2v, 512, 512, N);
}

// Round 6
// 211.745 us; speedup vs baseline: 1.3443x; 1.0051x over previous
//
#include <hip/hip_runtime.h>
#include <hip/hip_bf16.h>

// DotProductNonLocalBlock: B=8, C=512, N=3136 (pad 3200), E=256.
// No softmax => fully associative. Factored with DATA-INDEPENDENT
// P = wo·wv, Qt = wq^T·wk, u = wo·bv, r = bk^T·wq, w = Wk^T·bq, κ = bk·bq:
//   G  = X·X^T   [bf16 MFMA, split-K=2 col-interleaved partials, SYMMETRIC]
//   T  = Pd·Gp2 (K=1024 folds the reduce)
//   A2 = [T·Q + u·(Qt s)^T + (P s)·r^T]/N + u·r^T + I   (residual folded, R5 ✓)
//   a2 = [T·w + u·(s·w) + (P s)·κ]/N + u·κ + bo
//   Out = (A2+I)·X + a2
// Batch in blockIdx.x on all MFMA grids (XCD affinity; per-batch panels fit 4MB L2).
// LEDGER final GEMM: 64x128 single-buf = BEST | dbuf-drain/-128²/zero-LDS all worse.
// R5: identity-fold residual + prep/transpose merge: 228.6 -> 212.8, absmax
//   unchanged. New top kernel: prep_trans 48.8us @ 1.75 TB/s (22% HBM), VALU 8.6%,
//   occ 25% -> Little's-law starved (4 float4 in flight = 64B/thread; need ~4x).
// R6: transpose tile 64c x 128n, ALL 8 float4 loads hoisted ahead of processing
//   (clamped addr + post-zero select keeps them unconditional), LDS 33.3KB,
//   4 blocks/CU. Bank mapping preserved (2-way free). Mixed real/pad tile at
//   n0=3072 handled per-8-chunk.

typedef __attribute__((ext_vector_type(8))) __bf16 bf16x8;
typedef __attribute__((ext_vector_type(4))) float floatx4;

struct __align__(8) bh4 { __hip_bfloat16 x, y, z, w; };
struct __align__(16) bh8 { __hip_bfloat16 h[8]; };

__device__ __forceinline__ void load_lds16(const void* g, void* l) {
    __builtin_amdgcn_global_load_lds((const __attribute__((address_space(1))) void*)g,
                                     (__attribute__((address_space(3))) void*)l, 16, 0, 0);
}

// ---- fused: data-independent precompute + x transpose/convert ----
// z in [0,8): transpose_conv for batch z (tile 64c x 128n).
// z == 8: blk = y*25+x:
//   blk in [0,64)   -> Pd tile (P = wo·wv, duplicated [P|P])
//   blk in [64,128) -> Qt tile (wq^T·wk)
//   blk 128,129     -> u/r/w vectors (256 channels each)
//   blk 130         -> zero s accumulator
__global__ __launch_bounds__(256)
void prep_trans(const float* __restrict__ x, __hip_bfloat16* __restrict__ xT,
                __hip_bfloat16* __restrict__ xnp, float* __restrict__ s,
                const float* __restrict__ wo, const float* __restrict__ wv,
                const float* __restrict__ wq, const float* __restrict__ wk,
                const float* __restrict__ bq, const float* __restrict__ bk,
                const float* __restrict__ bv,
                __hip_bfloat16* __restrict__ Pdb, __hip_bfloat16* __restrict__ Qtb,
                float* __restrict__ u, float* __restrict__ r, float* __restrict__ w,
                float* __restrict__ kap)
{
    __shared__ __align__(16) float smem[128 * 65];   // 33.3KB arena, both paths
    const int tid = threadIdx.x;

    if (blockIdx.z == 8) {
        // ---------- prep path ----------
        const int blk = blockIdx.y * 25 + blockIdx.x;
        if (blk >= 131) return;
        if (blk >= 128) {
            int blk2 = blk - 128;
            if (blk2 < 2) {
                int c = blk2 * 256 + tid;
                float su = 0.f, sr = 0.f, sw = 0.f;
                for (int e = 0; e < 256; ++e) {
                    su = fmaf(wo[(long long)c * 256 + e], bv[e], su);
                    sr = fmaf(bk[e], wq[(long long)e * 512 + c], sr);
                    sw = fmaf(wk[(long long)e * 512 + c], bq[e], sw);
                }
                u[c] = su; r[c] = sr; w[c] = sw;
                if (c == 0) {
                    float k2 = 0.f;
                    for (int e = 0; e < 256; ++e) k2 = fmaf(bk[e], bq[e], k2);
                    *kap = k2;
                }
            } else {
                float4* p = (float4*)s;
                for (int i = tid; i < 1024; i += 256) p[i] = make_float4(0.f, 0.f, 0.f, 0.f);
            }
            return;
        }
        const bool doQ = (blk >= 64);
        const int tt = blk & 63;
        const int m0 = (tt >> 3) * 64, n0 = (tt & 7) * 64;
        float (*As)[68] = (float(*)[68])smem;
        float (*Bs)[68] = (float(*)[68])(smem + 16 * 68);
        const int tx = tid & 15, ty = tid >> 4;
        const int lk = tid >> 4, lc = (tid & 15) * 4;
        const int lr = tid >> 2, lk4 = (tid & 3) * 4;
        float acc[4][4] = {};
        for (int k0 = 0; k0 < 256; k0 += 16) {
            float4 av, bv4;
            if (doQ) {
                av = *(const float4*)&wq[(long long)(k0 + lk) * 512 + m0 + lc];
                bv4 = *(const float4*)&wk[(long long)(k0 + lk) * 512 + n0 + lc];
            } else {
                av = *(const float4*)&wo[(long long)(m0 + lr) * 256 + k0 + lk4];
                bv4 = *(const float4*)&wv[(long long)(k0 + lk) * 512 + n0 + lc];
            }
            __syncthreads();
            if (doQ) {
                *(float4*)&As[lk][lc] = av;
            } else {
                As[lk4 + 0][lr] = av.x; As[lk4 + 1][lr] = av.y;
                As[lk4 + 2][lr] = av.z; As[lk4 + 3][lr] = av.w;
            }
            *(float4*)&Bs[lk][lc] = bv4;
            __syncthreads();
#pragma unroll
            for (int kk = 0; kk < 16; ++kk) {
                float a[4], b[4];
#pragma unroll
                for (int i = 0; i < 4; ++i) { a[i] = As[kk][ty * 4 + i]; b[i] = Bs[kk][tx * 4 + i]; }
#pragma unroll
                for (int i = 0; i < 4; ++i)
#pragma unroll
                    for (int j = 0; j < 4; ++j) acc[i][j] = fmaf(a[i], b[j], acc[i][j]);
            }
        }
        const int mo = m0 + ty * 4, no = n0 + tx * 4;
        if (doQ) {
#pragma unroll
            for (int i = 0; i < 4; ++i)
#pragma unroll
                for (int j = 0; j < 4; ++j)
                    Qtb[(long long)(mo + i) * 512 + no + j] = __float2bfloat16(acc[i][j]);
        } else {
#pragma unroll
            for (int i = 0; i < 4; ++i)
#pragma unroll
                for (int j = 0; j < 4; ++j) {
                    __hip_bfloat16 v = __float2bfloat16(acc[i][j]);
                    Pdb[(long long)(mo + i) * 1024 + no + j] = v;
                    Pdb[(long long)(mo + i) * 1024 + no + j + 512] = v;
                }
        }
        return;
    }

    // ---------- transpose path: tile c[c0,c0+64) x n[n0,n0+128) ----------
    // x [b][512][3136] fp32 -> xT [b][3200][512] bf16 + xnp [b][512][3200] bf16
    //                        + s[b][c] += rowsums (atomic)
    // pass p: sub-tile s=p>>1 (n-halves), c-half = p&1. All 8 float4 loads
    // issued unconditionally up front (clamped addr, post-zero) for MLP.
    float (*t)[65] = (float(*)[65])smem;   // [128 n][65 c]
    const int b = blockIdx.z;
    const int n0 = blockIdx.x * 128, c0 = blockIdx.y * 64;
    const int nch = tid & 7;      // 8-float chunk within 64-col sub-tile
    const int cr  = tid >> 3;     // 0..31
    __hip_bfloat16* xTo = xT + (long long)b * 3200 * 512;
    __hip_bfloat16* xno = xnp + (long long)b * 512 * 3200;
    const float* xb = x + (long long)b * 512 * 3136;

    float4 v[4][2];
#pragma unroll
    for (int p = 0; p < 4; ++p) {
        const int c = c0 + cr + 32 * (p & 1);
        const int n = n0 + (p >> 1) * 64 + nch * 8;
        const float* xr = xb + (long long)c * 3136 + (n < 3136 ? n : 3128);
        v[p][0] = *(const float4*)xr;
        v[p][1] = *(const float4*)(xr + 4);
    }

    float rs0 = 0.f, rs1 = 0.f;
#pragma unroll
    for (int p = 0; p < 4; ++p) {
        const int cl = cr + 32 * (p & 1);
        const int c = c0 + cl;
        const int n = n0 + (p >> 1) * 64 + nch * 8;
        if (n >= 3136) {
            v[p][0] = make_float4(0.f, 0.f, 0.f, 0.f);
            v[p][1] = make_float4(0.f, 0.f, 0.f, 0.f);
        }
        float4 v0 = v[p][0], v1 = v[p][1];
        bh8 o;
        o.h[0] = __float2bfloat16(v0.x); o.h[1] = __float2bfloat16(v0.y);
        o.h[2] = __float2bfloat16(v0.z); o.h[3] = __float2bfloat16(v0.w);
        o.h[4] = __float2bfloat16(v1.x); o.h[5] = __float2bfloat16(v1.y);
        o.h[6] = __float2bfloat16(v1.z); o.h[7] = __float2bfloat16(v1.w);
        *(bh8*)&xno[(long long)c * 3200 + n] = o;
        const int nl = (p >> 1) * 64 + nch * 8;
        t[nl + 0][cl] = v0.x; t[nl + 1][cl] = v0.y;
        t[nl + 2][cl] = v0.z; t[nl + 3][cl] = v0.w;
        t[nl + 4][cl] = v1.x; t[nl + 5][cl] = v1.y;
        t[nl + 6][cl] = v1.z; t[nl + 7][cl] = v1.w;
        float rs = v0.x + v0.y + v0.z + v0.w + v1.x + v1.y + v1.z + v1.w;
        rs += __shfl_xor(rs, 1, 8);
        rs += __shfl_xor(rs, 2, 8);
        rs += __shfl_xor(rs, 4, 8);
        if (p & 1) rs1 += rs; else rs0 += rs;
    }
    if (nch == 0) {
        atomicAdd(&s[b * 512 + c0 + cr], rs0);
        atomicAdd(&s[b * 512 + c0 + cr + 32], rs1);
    }
    __syncthreads();
#pragma unroll
    for (int pp = 0; pp < 4; ++pp) {
        const int nl = cr + 32 * pp;     // 0..127
        const int cc = nch * 8;          // 0..63
        bh8 o;
#pragma unroll
        for (int k = 0; k < 8; ++k) o.h[k] = __float2bfloat16(t[nl][cc + k]);
        *(bh8*)&xTo[(long long)(n0 + nl) * 512 + c0 + cc] = o;
    }
}

// Wave-per-output: ps = P·s, sq = Qt·s, a2 = [T·w + u(s·w) + ps·κ]/N + uκ + bo.
__global__ __launch_bounds__(256)
void vec2_kernel(const __hip_bfloat16* __restrict__ T, const __hip_bfloat16* __restrict__ Pdb,
                 const __hip_bfloat16* __restrict__ Qtb, const float* __restrict__ s,
                 const float* __restrict__ u, const float* __restrict__ w,
                 const float* __restrict__ kap, const float* __restrict__ bo,
                 float* __restrict__ ps, float* __restrict__ sq, float* __restrict__ a2)
{
    const int idx = blockIdx.x * 4 + (threadIdx.x >> 6);   // b*512+c
    const int lane = threadIdx.x & 63;
    const int b = idx >> 9, c = idx & 511;
    const int j0 = lane * 8;
    const float* sb = s + b * 512;
    float4 s0 = *(const float4*)&sb[j0], s1 = *(const float4*)&sb[j0 + 4];
    float4 w0 = *(const float4*)&w[j0],  w1 = *(const float4*)&w[j0 + 4];
    bf16x8 pv = *(const bf16x8*)&Pdb[(long long)c * 1024 + j0];
    bf16x8 qv = *(const bf16x8*)&Qtb[(long long)c * 512 + j0];
    bf16x8 tv = *(const bf16x8*)&T[(long long)b * 262144 + (long long)c * 512 + j0];
    float sj[8] = {s0.x, s0.y, s0.z, s0.w, s1.x, s1.y, s1.z, s1.w};
    float wj[8] = {w0.x, w0.y, w0.z, w0.w, w1.x, w1.y, w1.z, w1.w};
    float aps = 0.f, asq = 0.f, atw = 0.f, asw = 0.f;
#pragma unroll
    for (int t = 0; t < 8; ++t) {
        aps = fmaf((float)pv[t], sj[t], aps);
        asq = fmaf((float)qv[t], sj[t], asq);
        atw = fmaf((float)tv[t], wj[t], atw);
        asw = fmaf(sj[t], wj[t], asw);
    }
#pragma unroll
    for (int m = 1; m < 64; m <<= 1) {
        aps += __shfl_xor(aps, m);
        asq += __shfl_xor(asq, m);
        atw += __shfl_xor(atw, m);
        asw += __shfl_xor(asw, m);
    }
    if (lane == 0) {
        ps[idx] = aps; sq[idx] = asq;
        float kp = *kap;
        a2[idx] = (atw + u[c] * asw + aps * kp) * (1.f / 3136.f) + u[c] * kp + bo[c];
    }
}

#define SWZ64(row) ((row) & 7)

// G GEMM with symmetric mirroring. 64x64 tile, BK=64, operands = xnp (both).
// Grid: x = batch + 8*ks (XCD affinity), y = triangular pair index (36).
// Counted-vmcnt double-buffered K-loop (neutral vs dbuf-drain, kept).
__global__ __launch_bounds__(256)
void mfma_g(const __hip_bfloat16* __restrict__ A, long long sA, int lda,
            __hip_bfloat16* __restrict__ C, long long sC, int ldc,
            int kLen)
{
    constexpr int BKT = 64;
    constexpr int CPR = BKT / 8;
    constexpr int NC = 64 * CPR / 256;
    constexpr int LSZ = 64 * BKT;
    __shared__ __hip_bfloat16 As[2 * LSZ];
    __shared__ __hip_bfloat16 Bs[2 * LSZ];
    const int tid = threadIdx.x;
    const int lane = tid & 63;
    const int w = tid >> 6;
    const int wm = (w >> 1) << 5;
    const int wn = (w & 1) << 5;
    const int ln = lane & 15;
    const int hi = lane >> 4;
    const int bx = blockIdx.x;
    const int batch = bx & 7, ks = bx >> 3;
    int p = blockIdx.y, mt = 0;
    while (p >= 8 - mt) { p -= 8 - mt; ++mt; }
    const int nt = mt + p;
    const int m0 = mt << 6, n0 = nt << 6;
    const long long k0 = (long long)ks * kLen;

    const __hip_bfloat16* gA[NC];
    const __hip_bfloat16* gB[NC];
#pragma unroll
    for (int q0 = 0; q0 < NC; ++q0) {
        int q = tid + 256 * q0;
        int row = q / CPR;
        int c = (q % CPR) ^ SWZ64(row);
        gA[q0] = A + batch * sA + (long long)(m0 + row) * lda + k0 + c * 8;
        gB[q0] = A + batch * sA + (long long)(n0 + row) * lda + k0 + c * 8;
    }
    floatx4 acc[2][2] = {};
    const int nK = kLen / BKT;

    // prologue: stage tile 0 into buffer 0 (4 loads/thread in flight)
#pragma unroll
    for (int q0 = 0; q0 < NC; ++q0) {
        load_lds16(gA[q0], As + (tid + 256 * q0) * 8);
        load_lds16(gB[q0], Bs + (tid + 256 * q0) * 8);
        gA[q0] += BKT; gB[q0] += BKT;
    }

    int cur = 0;
    for (int kt = 0; kt < nK; ++kt) {
        if (kt + 1 < nK) {
            const int off = (cur ^ 1) * LSZ;
#pragma unroll
            for (int q0 = 0; q0 < NC; ++q0) {
                load_lds16(gA[q0], As + off + (tid + 256 * q0) * 8);
                load_lds16(gB[q0], Bs + off + (tid + 256 * q0) * 8);
                gA[q0] += BKT; gB[q0] += BKT;
            }
            asm volatile("s_waitcnt vmcnt(4)" ::: "memory");   // cur tile landed; next in flight
        } else {
            asm volatile("s_waitcnt vmcnt(0)" ::: "memory");   // final tile landed
        }
        __builtin_amdgcn_s_barrier();
        const __hip_bfloat16* Ac = As + cur * LSZ;
        const __hip_bfloat16* Bc = Bs + cur * LSZ;
#pragma unroll
        for (int kk = 0; kk < BKT / 32; ++kk) {
            const int cidx = kk * 4 + hi;
            bf16x8 af[2], bfr[2];
#pragma unroll
            for (int i = 0; i < 2; ++i) {
                int row = wm + i * 16 + ln;
                af[i] = *(const bf16x8*)(Ac + row * BKT + ((cidx ^ SWZ64(row)) << 3));
            }
#pragma unroll
            for (int j = 0; j < 2; ++j) {
                int row = wn + j * 16 + ln;
                bfr[j] = *(const bf16x8*)(Bc + row * BKT + ((cidx ^ SWZ64(row)) << 3));
            }
#pragma unroll
            for (int i = 0; i < 2; ++i)
#pragma unroll
                for (int j = 0; j < 2; ++j)
                    acc[i][j] = __builtin_amdgcn_mfma_f32_16x16x32_bf16(af[i], bfr[j], acc[i][j], 0, 0, 0);
        }
        if (kt + 1 < nK) {
            __builtin_amdgcn_s_barrier();   // buf[cur] fully read -> safe to restage next iter
            cur ^= 1;
        }
    }

    // C/D layout: col = lane&15, row = (lane>>4)*4 + r  [m89-verified]
    __hip_bfloat16* Cb = C + batch * sC + ks * 512;
#pragma unroll
    for (int i = 0; i < 2; ++i) {
        int mb = m0 + wm + i * 16 + hi * 4;
#pragma unroll
        for (int j = 0; j < 2; ++j) {
            int nl = n0 + wn + j * 16 + ln;
            bh4 mv;
            mv.x = __float2bfloat16(acc[i][j][0]);
            mv.y = __float2bfloat16(acc[i][j][1]);
            mv.z = __float2bfloat16(acc[i][j][2]);
            mv.w = __float2bfloat16(acc[i][j][3]);
            Cb[(long long)(mb + 0) * ldc + nl] = mv.x;
            Cb[(long long)(mb + 1) * ldc + nl] = mv.y;
            Cb[(long long)(mb + 2) * ldc + nl] = mv.z;
            Cb[(long long)(mb + 3) * ldc + nl] = mv.w;
            if (mt != nt)
                *(bh4*)&Cb[(long long)nl * ldc + mb] = mv;   // mirrored tile
        }
    }
}

// Small MFMA GEMM, 64x64 tile, BK=64, operands K-contiguous.
// MODE 5: plain bf16 store.
// MODE 6: bf16 store of (acc + u[m]·sq[b][n] + ps[b][m]·r[n])/N + u[m]·r[n]
//         + IDENTITY on the diagonal (residual x folded into A2).
// Counted-vmcnt double-buffered K-loop.
template<int MODE>
__global__ __launch_bounds__(256)
void mfma_sm(const __hip_bfloat16* __restrict__ A, long long sA, int lda,
             const __hip_bfloat16* __restrict__ B, long long sB, int ldb,
             __hip_bfloat16* __restrict__ C, long long sC, int ldc,
             const float* __restrict__ pu, const float* __restrict__ pr,
             const float* __restrict__ pps, const float* __restrict__ psq,
             int kLen)
{
    constexpr int BKT = 64;
    constexpr int CPR = BKT / 8;
    constexpr int NC = 64 * CPR / 256;
    constexpr int LSZ = 64 * BKT;
    __shared__ __hip_bfloat16 As[2 * LSZ];
    __shared__ __hip_bfloat16 Bs[2 * LSZ];
    const int tid = threadIdx.x;
    const int lane = tid & 63;
    const int w = tid >> 6;
    const int wm = (w >> 1) << 5;
    const int wn = (w & 1) << 5;
    const int ln = lane & 15;
    const int hi = lane >> 4;
    const int batch = blockIdx.x;
    const int m0 = blockIdx.z << 6;
    const int n0 = blockIdx.y << 6;

    const __hip_bfloat16* gA[NC];
    const __hip_bfloat16* gB[NC];
#pragma unroll
    for (int q0 = 0; q0 < NC; ++q0) {
        int q = tid + 256 * q0;
        int row = q / CPR;
        int c = (q % CPR) ^ SWZ64(row);
        gA[q0] = A + batch * sA + (long long)(m0 + row) * lda + c * 8;
        gB[q0] = B + batch * sB + (long long)(n0 + row) * ldb + c * 8;
    }
    floatx4 acc[2][2] = {};
    const int nK = kLen / BKT;

#pragma unroll
    for (int q0 = 0; q0 < NC; ++q0) {
        load_lds16(gA[q0], As + (tid + 256 * q0) * 8);
        load_lds16(gB[q0], Bs + (tid + 256 * q0) * 8);
        gA[q0] += BKT; gB[q0] += BKT;
    }

    int cur = 0;
    for (int kt = 0; kt < nK; ++kt) {
        if (kt + 1 < nK) {
            const int off = (cur ^ 1) * LSZ;
#pragma unroll
            for (int q0 = 0; q0 < NC; ++q0) {
                load_lds16(gA[q0], As + off + (tid + 256 * q0) * 8);
                load_lds16(gB[q0], Bs + off + (tid + 256 * q0) * 8);
                gA[q0] += BKT; gB[q0] += BKT;
            }
            asm volatile("s_waitcnt vmcnt(4)" ::: "memory");
        } else {
            asm volatile("s_waitcnt vmcnt(0)" ::: "memory");
        }
        __builtin_amdgcn_s_barrier();
        const __hip_bfloat16* Ac = As + cur * LSZ;
        const __hip_bfloat16* Bc = Bs + cur * LSZ;
#pragma unroll
        for (int kk = 0; kk < BKT / 32; ++kk) {
            const int cidx = kk * 4 + hi;
            bf16x8 af[2], bfr[2];
#pragma unroll
            for (int i = 0; i < 2; ++i) {
                int row = wm + i * 16 + ln;
                af[i] = *(const bf16x8*)(Ac + row * BKT + ((cidx ^ SWZ64(row)) << 3));
            }
#pragma unroll
            for (int j = 0; j < 2; ++j) {
                int row = wn + j * 16 + ln;
                bfr[j] = *(const bf16x8*)(Bc + row * BKT + ((cidx ^ SWZ64(row)) << 3));
            }
#pragma unroll
            for (int i = 0; i < 2; ++i)
#pragma unroll
                for (int j = 0; j < 2; ++j)
                    acc[i][j] = __builtin_amdgcn_mfma_f32_16x16x32_bf16(af[i], bfr[j], acc[i][j], 0, 0, 0);
        }
        if (kt + 1 < nK) {
            __builtin_amdgcn_s_barrier();
            cur ^= 1;
        }
    }

    __hip_bfloat16* Cb = C + batch * sC;
#pragma unroll
    for (int i = 0; i < 2; ++i) {
        int mb = m0 + wm + i * 16 + hi * 4;
#pragma unroll
        for (int r = 0; r < 4; ++r) {
#pragma unroll
            for (int j = 0; j < 2; ++j) {
                int nl = n0 + wn + j * 16 + ln;
                float v = acc[i][j][r];
                if (MODE == 6) {
                    float uu = pu[mb + r], rr = pr[nl];
                    v = (v + uu * psq[batch * 512 + nl] + pps[batch * 512 + mb + r] * rr)
                        * (1.f / 3136.f) + uu * rr;
                    if (mb + r == nl) v += 1.f;   // residual fold: A2 += I
                }
                Cb[(long long)(mb + r) * ldc + nl] = __float2bfloat16(v);
            }
        }
    }
}

// Final MFMA GEMM: 64(M)x128(N) tile, 4 waves (64x32 each), BK=64.
// R0 structure (measured best). Residual folded into A2 -> no x read;
// epilogue = acc + bias only.
__global__ __launch_bounds__(256)
void mfma64(const __hip_bfloat16* __restrict__ A, long long sA, int lda,
            const __hip_bfloat16* __restrict__ B, long long sB, int ldb,
            float* __restrict__ C, long long sC, int ldc,
            const float* __restrict__ bias, int sBias,
            int kLen, int Nreal)
{
    constexpr int BKT = 64;
    constexpr int CPR = BKT / 8;
    constexpr int NA = 64 * CPR / 256;
    constexpr int NB = 128 * CPR / 256;
    __shared__ __hip_bfloat16 As[64 * BKT];
    __shared__ __hip_bfloat16 Bs[128 * BKT];
    const int tid = threadIdx.x;
    const int lane = tid & 63;
    const int w = tid >> 6;
    const int ln = lane & 15;
    const int hi = lane >> 4;
    const int batch = blockIdx.x;
    const int m0 = blockIdx.z << 6;
    const int n0 = blockIdx.y << 7;

    const __hip_bfloat16* gA[NA];
    const __hip_bfloat16* gB[NB];
#pragma unroll
    for (int q0 = 0; q0 < NA; ++q0) {
        int q = tid + 256 * q0;
        int row = q / CPR;
        int c = (q % CPR) ^ SWZ64(row);
        gA[q0] = A + batch * sA + (long long)(m0 + row) * lda + c * 8;
    }
#pragma unroll
    for (int q0 = 0; q0 < NB; ++q0) {
        int q = tid + 256 * q0;
        int row = q / CPR;
        int c = (q % CPR) ^ SWZ64(row);
        gB[q0] = B + batch * sB + (long long)(n0 + row) * ldb + c * 8;
    }

    floatx4 acc[4][2] = {};
    const int nK = kLen / BKT;
    for (int kt = 0; kt < nK; ++kt) {
#pragma unroll
        for (int q0 = 0; q0 < NA; ++q0) {
            load_lds16(gA[q0], As + (tid + 256 * q0) * 8);
            gA[q0] += BKT;
        }
#pragma unroll
        for (int q0 = 0; q0 < NB; ++q0) {
            load_lds16(gB[q0], Bs + (tid + 256 * q0) * 8);
            gB[q0] += BKT;
        }
        __syncthreads();
#pragma unroll
        for (int kk = 0; kk < BKT / 32; ++kk) {
            const int cidx = kk * 4 + hi;
            bf16x8 af[4], bfr[2];
#pragma unroll
            for (int i = 0; i < 4; ++i) {
                int row = i * 16 + ln;
                af[i] = *(const bf16x8*)(As + row * BKT + ((cidx ^ SWZ64(row)) << 3));
            }
#pragma unroll
            for (int j = 0; j < 2; ++j) {
                int row = w * 32 + j * 16 + ln;
                bfr[j] = *(const bf16x8*)(Bs + row * BKT + ((cidx ^ SWZ64(row)) << 3));
            }
#pragma unroll
            for (int i = 0; i < 4; ++i)
#pragma unroll
                for (int j = 0; j < 2; ++j)
                    acc[i][j] = __builtin_amdgcn_mfma_f32_16x16x32_bf16(af[i], bfr[j], acc[i][j], 0, 0, 0);
        }
        __syncthreads();
    }

    float* Cb = C + batch * sC;
#pragma unroll
    for (int i = 0; i < 4; ++i) {
        int mb = m0 + i * 16 + hi * 4;
#pragma unroll
        for (int r = 0; r < 4; ++r) {
            float bb = bias[batch * sBias + mb + r];
#pragma unroll
            for (int j = 0; j < 2; ++j) {
                int nl = n0 + w * 32 + j * 16 + ln;
                if (nl < Nreal) {
                    Cb[(long long)(mb + r) * ldc + nl] = acc[i][j][r] + bb;
                }
            }
        }
    }
}

extern "C" void kernel_launch(void* const* d_in, const int* in_sizes, int n_in,
                              void* d_out, int out_size, void* d_ws, size_t ws_size,
                              hipStream_t stream)
{
    const float* x  = (const float*)d_in[0];
    const float* wq = (const float*)d_in[1];
    const float* bq = (const float*)d_in[2];
    const float* wk = (const float*)d_in[3];
    const float* bk = (const float*)d_in[4];
    const float* wv = (const float*)d_in[5];
    const float* bv = (const float*)d_in[6];
    const float* wo = (const float*)d_in[7];
    const float* bo = (const float*)d_in[8];
    float* out = (float*)d_out;

    const int N = 3136;
    const long long xs = 512LL * N;               // 1,605,632
    const long long xs2 = 512LL * 3200;           // xnp per-batch stride

    // d_out scratch (51.4 MB), all dead before the final GEMM writes out:
    char* ob = (char*)d_out;
    __hip_bfloat16* xnp = (__hip_bfloat16*)ob;                 // @0: 26,214,400 (dead after G)
    __hip_bfloat16* Gp2 = (__hip_bfloat16*)(ob + 26214400);    // 8x512x1024 bf16 = 8,388,608
    __hip_bfloat16* Tb  = (__hip_bfloat16*)(ob + 34603008);    // 8x512x512 bf16 = 4,194,304

    // ws (~32.05 MB). Final GEMM reads only ws.
    char* wsb = (char*)d_ws;
    __hip_bfloat16* xT  = (__hip_bfloat16*)wsb;                // 26,214,400
    __hip_bfloat16* A2b = (__hip_bfloat16*)(wsb + 26214400);   //  4,194,304
    __hip_bfloat16* Pdb = (__hip_bfloat16*)(wsb + 30408704);   //  1,048,576
    __hip_bfloat16* Qtb = (__hip_bfloat16*)(wsb + 31457280);   //    524,288
    float* sv  = (float*)(wsb + 31981568);                     //     16,384
    float* u_  = (float*)(wsb + 31997952);                     //      2,048
    float* r_  = (float*)(wsb + 32000000);                     //      2,048
    float* w_  = (float*)(wsb + 32002048);                     //      2,048
    float* kap = (float*)(wsb + 32004096);                     //         16
    float* ps  = (float*)(wsb + 32004112);                     //     16,384
    float* sq  = (float*)(wsb + 32020496);                     //     16,384
    float* a2v = (float*)(wsb + 32036880);                     //     16,384

    // 1) fused: precompute (P/Qt/u/r/w/kap + zero s) + xT/xnp/s transpose
    //    transpose tile 64c x 128n -> 25 x-blocks; prep rides z=8 (131/200 blocks)
    prep_trans<<<dim3(25, 8, 9), 256, 0, stream>>>(
        x, xT, xnp, sv, wo, wv, wq, wk, bq, bk, bv,
        Pdb, Qtb, u_, r_, w_, kap);

    // 2) Gp2 = partials of X·X^T  (split-K=2, K=1600, BK=64), symmetric:
    //    36 upper-tri tile pairs x 16 (batch,ks) = 576 blocks, mirror on store
    mfma_g<<<dim3(16, 36), 256, 0, stream>>>(
        xnp, xs2, 3200, Gp2, 524288, 1024, 1600);

    // 3) T = Pd·Gp2  (K=1024 folds the split-K reduce)
    mfma_sm<5><<<dim3(8, 8, 8), 256, 0, stream>>>(
        Pdb, 0, 1024, Gp2, 524288, 1024, Tb, 262144, 512,
        nullptr, nullptr, nullptr, nullptr, 1024);

    // 4) ps = P·s, sq = Qt·s, a2 = [T·w + u(s·w) + ps·κ]/N + uκ + bo
    vec2_kernel<<<1024, 256, 0, stream>>>(Tb, Pdb, Qtb, sv, u_, w_, kap, bo, ps, sq, a2v);

    // 5) A2 = [T·Q + u·sq^T + ps·r^T]/N + u·r^T + I  -> bf16 (residual folded)
    mfma_sm<6><<<dim3(8, 8, 8), 256, 0, stream>>>(
        Tb, 262144, 512, Qtb, 0, 512, A2b, 262144, 512,
        u_, r_, ps, sq, 512);

    // 6) out = (A2+I)·X + a2   (M=512, N=3136, K=512)
    mfma64<<<dim3(8, 25, 8), 256, 0, stream>>>(
        A2b, 262144, 512, xT, 3200LL * 512, 512,
        out, xs, N, a2v, 512, 512, N);
}